// Round 6
// baseline (4106.678 us; speedup 1.0000x reference)
//
#include <hip/hip_runtime.h>

// Sizes
#define B_   32
#define S_   64
#define T_   64
#define H_   1024
#define H2_  2048
#define E_   512
#define V_   32000
#define K3_  3072
#define BT_  2048

typedef unsigned short u16;
typedef __attribute__((ext_vector_type(8))) short short8_t;  // 8 x bf16
typedef __attribute__((ext_vector_type(4))) float f32x4;

__device__ __forceinline__ u16 f2bf(float f) {
  unsigned x = __float_as_uint(f);
  unsigned r = (x + 0x7fffu + ((x >> 16) & 1u)) >> 16;  // RNE
  return (u16)r;
}
__device__ __forceinline__ float bf2f(u16 h) {
  return __uint_as_float(((unsigned)h) << 16);
}
__device__ __forceinline__ float frcp(float x) { return __builtin_amdgcn_rcpf(x); }
__device__ __forceinline__ float ftanh(float x) {
  float e = __expf(2.f * x);
  return 1.f - 2.f * frcp(e + 1.f);
}
__device__ __forceinline__ float fsigm(float x) {
  return frcp(1.f + __expf(-x));
}

// pin a loaded value in VGPRs: opaque asm result cannot be rematerialized
#define KEEPV(x) asm volatile("" : "+v"(x))

// write-through to the coherent point (LLC) — visible cross-XCD, no fence
__device__ __forceinline__ void st_u16(u16* p, u16 v) {
  __hip_atomic_store(p, v, __ATOMIC_RELAXED, __HIP_MEMORY_SCOPE_AGENT);
}
__device__ __forceinline__ void st_f32(float* p, float v) {
  __hip_atomic_store(p, v, __ATOMIC_RELAXED, __HIP_MEMORY_SCOPE_AGENT);
}

// ---------------- workspace layout (bytes) ----------------
#define MB_ (1ull << 20)
#define KB_ (1ull << 10)
#define X_OFF    (0)              // 4MB; encp aliases after xgr/xg2 gemms
#define XGR_OFF  (4*MB_)          // 8MB
#define XG2_OFF  (12*MB_)         // 8MB
#define ENCT_OFF (20*MB_)         // 8MB (pre-loop only)
#define QFV_OFF  (20*MB_)         // qf versions t=0..63 x 128KB (aliases encT)
#define WQF_OFF  (28*MB_)         // 2MB (pre-loop only)
#define WGF_OFF  (30*MB_)         // 24MB (pre-loop only)
#define XSV_OFF  (28*MB_)         // Xs versions t=1..64 x 128KB -> [28,36)
#define XCV_OFF  (36*MB_)         // Xc versions t=0..63 x 256KB -> [36,52)
#define WOT_OFF  (0)              // 32MB (after mega only)
#define DECH_OFF (54*MB_)         // 4MB
#define XS0_OFF  (58*MB_)         // 128KB (Xs version 0, written pre-barrier)
#define BAS_OFF  (58*MB_ + 128*KB_)   // 4KB
#define BCR_OFF  (58*MB_ + 132*KB_)   // 4KB
#define BC2_OFF  (58*MB_ + 136*KB_)   // 4KB
#define WLB_OFF  (58*MB_ + 140*KB_)   // 2KB
#define BAR_OFF  (58*MB_ + 144*KB_)   // 4KB

// version-buffer address helpers
__device__ __forceinline__ u16* xs_hi(char* w, int t) {
  return (u16*)(t == 0 ? (w + XS0_OFF) : (w + XSV_OFF + (size_t)(t - 1) * 131072));
}
__device__ __forceinline__ u16* xc_hi(char* w, int t) {
  return (u16*)(w + XCV_OFF + (size_t)t * 262144);
}
__device__ __forceinline__ float* qf_v(char* w, int t) {
  return (float*)(w + QFV_OFF + (size_t)t * 131072);
}

// ---------------- prologue kernels ----------------

__global__ void k_gather(float* __restrict__ x, const float* __restrict__ embed,
                         const int* __restrict__ tgt) {
  int bid = blockIdx.x;              // t*B + b
  int t = bid >> 5, b = bid & 31;
  int row = tgt[b * T_ + t];
  const float4* src = (const float4*)(embed + (size_t)row * E_);
  float4* dst = (float4*)(x + (size_t)bid * E_);
  dst[threadIdx.x] = src[threadIdx.x];
}

__global__ void k_biascomb(float* bcr, float* bc2o, float* bas, u16* wlb,
                           const float* bi, const float* bh, const float* bc,
                           const float* bi2, const float* bh2, const float* bc2i,
                           const float* benc, const float* bprev, const float* wlin) {
  int j = blockIdx.x * 256 + threadIdx.x;
  if (j < H_) {
    bcr[j]  = bi[j]  + bh[j]  + bc[j];
    bc2o[j] = bi2[j] + bh2[j] + bc2i[j];
    bas[j]  = benc[j] + bprev[j];
    wlb[j]  = f2bf(wlin[j]);
  }
}

// generic 128x128 bf16-MFMA GEMM (fp32 in, fp32/bf16 out) — prologue only
__global__ __launch_bounds__(256) void k_gemm(
    const float* __restrict__ A, int lda,
    const float* __restrict__ Bm, int ldb,
    void* __restrict__ Cv, int ldc, int outBf16,
    const float* __restrict__ bias,
    int mtiles, int ntiles, int K) {
  __shared__ u16 As[128][72];
  __shared__ u16 Bs[128][72];
  int nwg = mtiles * ntiles;
  int bid = blockIdx.x;
  int cpx = nwg >> 3;
  int lb = (bid & 7) * cpx + (bid >> 3);
  int ntb = lb / mtiles, mtb = lb - ntb * mtiles;
  size_t m0 = (size_t)mtb * 128, n0 = (size_t)ntb * 128;
  int t = threadIdx.x, lane = t & 63, wid = t >> 6;
  int wr = (wid >> 1) * 64, wc = (wid & 1) * 64;
  f32x4 acc[4][4] = {};
  for (int k0 = 0; k0 < K; k0 += 64) {
    #pragma unroll
    for (int i = 0; i < 8; ++i) {
      int f4 = i * 256 + t;
      int row = f4 >> 4, c4 = (f4 & 15) << 2;
      float4 v = *(const float4*)(A + (m0 + row) * (size_t)lda + k0 + c4);
      ushort4 u; u.x = f2bf(v.x); u.y = f2bf(v.y); u.z = f2bf(v.z); u.w = f2bf(v.w);
      *(ushort4*)&As[row][c4] = u;
    }
    #pragma unroll
    for (int i = 0; i < 8; ++i) {
      int f4 = i * 256 + t;
      int kr = f4 >> 5, c4 = (f4 & 31) << 2;
      float4 v = *(const float4*)(Bm + (size_t)(k0 + kr) * ldb + n0 + c4);
      Bs[c4 + 0][kr] = f2bf(v.x);
      Bs[c4 + 1][kr] = f2bf(v.y);
      Bs[c4 + 2][kr] = f2bf(v.z);
      Bs[c4 + 3][kr] = f2bf(v.w);
    }
    __syncthreads();
    #pragma unroll
    for (int kk = 0; kk < 64; kk += 32) {
      int ko = kk + (lane >> 4) * 8;
      short8_t am[4], bn[4];
      #pragma unroll
      for (int m = 0; m < 4; ++m) am[m] = *(const short8_t*)&As[wr + m * 16 + (lane & 15)][ko];
      #pragma unroll
      for (int n = 0; n < 4; ++n) bn[n] = *(const short8_t*)&Bs[wc + n * 16 + (lane & 15)][ko];
      #pragma unroll
      for (int m = 0; m < 4; ++m)
        #pragma unroll
        for (int n = 0; n < 4; ++n)
          acc[m][n] = __builtin_amdgcn_mfma_f32_16x16x32_bf16(am[m], bn[n], acc[m][n], 0, 0, 0);
    }
    __syncthreads();
  }
  #pragma unroll
  for (int n = 0; n < 4; ++n) {
    int col = wc + n * 16 + (lane & 15);
    float bv = bias ? bias[n0 + col] : 0.f;
    #pragma unroll
    for (int m = 0; m < 4; ++m) {
      size_t row = m0 + wr + m * 16 + ((lane >> 4) << 2);
      #pragma unroll
      for (int r = 0; r < 4; ++r) {
        float val = acc[m][n][r] + bv;
        if (outBf16) ((u16*)Cv)[(row + r) * (size_t)ldc + n0 + col] = f2bf(val);
        else ((float*)Cv)[(row + r) * (size_t)ldc + n0 + col] = val;
      }
    }
  }
}

// enc_h -> encT[e][b*64+si] bf16
__global__ __launch_bounds__(256) void k_transE(u16* __restrict__ encT,
                                                const float* __restrict__ enc_h) {
  __shared__ u16 ld[64][68];
  int b = blockIdx.x >> 5, et = blockIdx.x & 31;
  int e0 = et * 64;
  int t = threadIdx.x;
  #pragma unroll
  for (int i = 0; i < 4; ++i) {
    int f4 = i * 256 + t;
    int si = f4 >> 4, e4 = (f4 & 15) << 2;
    float4 v = *(const float4*)(enc_h + ((size_t)(b * 64 + si)) * H2_ + e0 + e4);
    ld[si][e4 + 0] = f2bf(v.x); ld[si][e4 + 1] = f2bf(v.y);
    ld[si][e4 + 2] = f2bf(v.z); ld[si][e4 + 3] = f2bf(v.w);
  }
  __syncthreads();
  #pragma unroll
  for (int i = 0; i < 2; ++i) {
    int idx = i * 256 + t;
    int e = idx >> 3, s8 = (idx & 7) << 3;
    short8_t o;
    #pragma unroll
    for (int k = 0; k < 8; ++k) o[k] = (short)ld[s8 + k][e];
    *(short8_t*)(encT + ((size_t)(e0 + e)) * 2048 + b * 64 + s8) = o;
  }
}

// att_Wprev -> wqf frag-major bf16 (LDS-tiled, coalesced source reads)
__global__ __launch_bounds__(256) void k_packq(u16* __restrict__ wqf,
                                               const float* __restrict__ W) {
  __shared__ float ld[64][33];
  int jt = blockIdx.x & 31, kt = blockIdx.x >> 5;   // 32 x 16
  int c0 = jt * 32, k0 = kt * 64;
  int t = threadIdx.x;
  #pragma unroll
  for (int i = 0; i < 8; ++i) {
    int idx = i * 256 + t; int kr = idx >> 5, jc = idx & 31;
    ld[kr][jc] = W[(size_t)(k0 + kr) * H_ + c0 + jc];
  }
  __syncthreads();
  int u = t;
  int gl = u >> 7, kbl = (u >> 6) & 1, sub = (u >> 4) & 3, c = u & 15;
  int colLoc = gl * 16 + c;
  int gG = jt * 2 + gl, KB = kt * 2 + kbl;
  size_t lin = ((size_t)(gG * 32 + KB) * 4 + sub) * 16 + c;
  short8_t o;
  #pragma unroll
  for (int j = 0; j < 8; ++j) o[j] = (short)f2bf(ld[kbl * 32 + sub * 8 + j][colLoc]);
  *(short8_t*)(wqf + lin * 8) = o;
}

// gate weights -> wgf frag-major (hi in c<8, lo in c>=8), LDS-tiled
__global__ __launch_bounds__(256) void k_packg(
    u16* __restrict__ wgf, const float* __restrict__ Wh, const float* __restrict__ Wc,
    const float* __restrict__ Wh2, const float* __restrict__ Wc2) {
  __shared__ float ld[64][33];
  int sel = blockIdx.x & 1;
  int jt  = (blockIdx.x >> 1) & 31;
  int kt  = blockIdx.x >> 6;          // 0..47
  int k0 = kt * 64, j0 = jt * 32;
  int t = threadIdx.x;
  const float* srcW = (k0 < H_) ? (sel ? Wh2 : Wh) : (sel ? Wc2 : Wc);
  int ldw = sel ? H_ : H2_;
  int koff = (k0 < H_) ? k0 : (k0 - H_);
  #pragma unroll
  for (int i = 0; i < 8; ++i) {
    int idx = i * 256 + t; int kr = idx >> 5, jc = idx & 31;
    ld[kr][jc] = srcW[(size_t)(koff + kr) * ldw + j0 + jc];
  }
  __syncthreads();
  #pragma unroll
  for (int it = 0; it < 2; ++it) {
    int u = it * 256 + t;
    int m = u & 3, sub = (u >> 2) & 3, kbl = (u >> 4) & 1, islo = (u >> 5) & 1, gg = u >> 6;
    int jjLoc = gg * 4 + m;
    int p = 2 * (j0 + jjLoc) + sel;
    int g = p >> 3, cc = p & 7;
    int c = cc + 8 * islo;
    int KB = kt * 2 + kbl;
    size_t lin = ((size_t)(g * 96 + KB) * 4 + sub) * 16 + c;
    short8_t o;
    #pragma unroll
    for (int j = 0; j < 8; ++j) {
      float v = ld[kbl * 32 + sub * 8 + j][jjLoc];
      u16 h = f2bf(v);
      o[j] = (short)(islo ? f2bf(v - bf2f(h)) : h);
    }
    *(short8_t*)(wgf + lin * 8) = o;
  }
}

// out_W half -> wot bf16 [nLocal 16000][k 1024]
__global__ __launch_bounds__(256) void k_wtrans(u16* __restrict__ wot,
                                                const float* __restrict__ W, int nbase) {
  __shared__ u16 ld[64][68];
  int nt = blockIdx.x % 250, kt = blockIdx.x / 250;
  int n0 = nbase + nt * 64, k0 = kt * 64;
  int t = threadIdx.x;
  #pragma unroll
  for (int i = 0; i < 4; ++i) {
    int f4 = i * 256 + t;
    int kr = f4 >> 4, n4 = (f4 & 15) << 2;
    float4 v = *(const float4*)(W + (size_t)(k0 + kr) * V_ + n0 + n4);
    ld[kr][n4 + 0] = f2bf(v.x); ld[kr][n4 + 1] = f2bf(v.y);
    ld[kr][n4 + 2] = f2bf(v.z); ld[kr][n4 + 3] = f2bf(v.w);
  }
  __syncthreads();
  #pragma unroll
  for (int i = 0; i < 2; ++i) {
    int idx = i * 256 + t;
    int n = idx >> 3, k8 = (idx & 7) << 3;
    short8_t o;
    #pragma unroll
    for (int k = 0; k < 8; ++k) o[k] = (short)ld[k8 + k][n];
    *(short8_t*)(wot + ((size_t)(nt * 64 + n)) * H_ + k0 + k8) = o;
  }
}

// final GEMM: dech bf16 [2048][1024] @ wot^T -> C fp32 (per 16000-col half)
__global__ __launch_bounds__(256) void k_gemm2(
    const u16* __restrict__ A, const u16* __restrict__ Bt,
    float* __restrict__ C, const float* __restrict__ bias, int n0g) {
  __shared__ u16 As[128][72];
  __shared__ u16 Bs[128][72];
  int bid = blockIdx.x;
  int lb = (bid & 7) * 250 + (bid >> 3);
  int mtb = lb & 15, ntb = lb >> 4;
  size_t m0 = (size_t)mtb * 128;
  size_t nl0 = (size_t)ntb * 128;
  int t = threadIdx.x, lane = t & 63, wid = t >> 6;
  int wr = (wid >> 1) * 64, wc = (wid & 1) * 64;
  f32x4 acc[4][4] = {};
  for (int k0 = 0; k0 < H_; k0 += 64) {
    #pragma unroll
    for (int i = 0; i < 4; ++i) {
      int idx = i * 256 + t;
      int row = idx >> 3, c8 = (idx & 7) << 3;
      *(short8_t*)&As[row][c8] = *(const short8_t*)(A + (m0 + row) * H_ + k0 + c8);
      *(short8_t*)&Bs[row][c8] = *(const short8_t*)(Bt + (nl0 + row) * H_ + k0 + c8);
    }
    __syncthreads();
    #pragma unroll
    for (int kk = 0; kk < 64; kk += 32) {
      int ko = kk + (lane >> 4) * 8;
      short8_t am[4], bn[4];
      #pragma unroll
      for (int m = 0; m < 4; ++m) am[m] = *(const short8_t*)&As[wr + m * 16 + (lane & 15)][ko];
      #pragma unroll
      for (int n = 0; n < 4; ++n) bn[n] = *(const short8_t*)&Bs[wc + n * 16 + (lane & 15)][ko];
      #pragma unroll
      for (int m = 0; m < 4; ++m)
        #pragma unroll
        for (int n = 0; n < 4; ++n)
          acc[m][n] = __builtin_amdgcn_mfma_f32_16x16x32_bf16(am[m], bn[n], acc[m][n], 0, 0, 0);
    }
    __syncthreads();
  }
  #pragma unroll
  for (int n = 0; n < 4; ++n) {
    int col = n0g + (int)nl0 + wc + n * 16 + (lane & 15);
    float bv = bias[col];
    #pragma unroll
    for (int m = 0; m < 4; ++m) {
      size_t row = m0 + wr + m * 16 + ((lane >> 4) << 2);
      #pragma unroll
      for (int r = 0; r < 4; ++r)
        C[(row + r) * (size_t)V_ + col] = acc[m][n][r] + bv;
    }
  }
}

// ---------------- persistent decoder kernel ----------------

// relaxed barrier: no cache maintenance (versioned buffers give freshness)
__device__ __forceinline__ void gridbar(int* bar, int target) {
  asm volatile("s_waitcnt vmcnt(0)" ::: "memory");
  __syncthreads();
  if (threadIdx.x == 0) {
    int* leaf  = bar;                 // 32 x 16 ints
    int* root  = bar + 512;
    int* epoch = bar + 528;
    int li = (blockIdx.x >> 3) * 16;
    if (__hip_atomic_fetch_add(&leaf[li], 1, __ATOMIC_RELAXED, __HIP_MEMORY_SCOPE_AGENT) == 7) {
      __hip_atomic_store(&leaf[li], 0, __ATOMIC_RELAXED, __HIP_MEMORY_SCOPE_AGENT);
      if (__hip_atomic_fetch_add(root, 1, __ATOMIC_RELAXED, __HIP_MEMORY_SCOPE_AGENT) == 31) {
        __hip_atomic_store(root, 0, __ATOMIC_RELAXED, __HIP_MEMORY_SCOPE_AGENT);
        __hip_atomic_store(epoch, target, __ATOMIC_RELAXED, __HIP_MEMORY_SCOPE_AGENT);
      }
    }
    while (__hip_atomic_load(epoch, __ATOMIC_RELAXED, __HIP_MEMORY_SCOPE_AGENT) != target)
      __builtin_amdgcn_s_sleep(1);
  }
  __syncthreads();
}

#define MFMA16(a, b, c) __builtin_amdgcn_mfma_f32_16x16x32_bf16((a), (b), (c), 0, 0, 0)

// 1024 threads = 16 waves = 4 waves/SIMD: double the latency hiding of r5.
__global__ __launch_bounds__(1024, 4) void k_mega(
    char* w, u16* __restrict__ dech, float* __restrict__ fout,
    const u16* __restrict__ wqf, const u16* __restrict__ wgf,
    const u16* __restrict__ encp, const u16* __restrict__ encT,
    const float* __restrict__ xgr, const float* __restrict__ xg2,
    const float* __restrict__ prev_s, const u16* __restrict__ wlb,
    int* bar) {
  const int t = threadIdx.x, blk = blockIdx.x;
  const int lane = t & 63, wid = t >> 6;     // wid 0..15
  const int l15 = lane & 15, l4 = lane >> 4;
  const int klo = l4 * 8;
  __shared__ short8_t wg_lds[6144];   // 96KB — gate weights, LDS-resident
  __shared__ f32x4 scr[2048];         // 32KB reduce scratch (16 waves x 2)
  __shared__ float sc[64];
  int ep = 0;

  // LDS-resident gate-weight slice (per block), loaded ONCE (pre-loop only)
  for (int i = t; i < 6144; i += 1024)
    wg_lds[i] = *(const short8_t*)(wgf + ((size_t)blk * 6144 + i) * 8);

  // ---- register-resident operands, loaded ONCE and pinned (KEEPV) ----
  // P1: block gq (<64 active); wave owns kb = wid*2 + {0,1}
  const int gq = blk & 63;
  short8_t wq[2];
  #pragma unroll
  for (int i = 0; i < 2; ++i) {
    wq[i] = *(const short8_t*)(wqf + ((size_t)(gq * 32 + wid * 2 + i) * 64 + lane) * 8);
    KEEPV(wq[i]);
  }
  // P2: b = blk>>3, eg = blk&7 ; wave covers si = wid*4..+4, lane covers j = lane*16..+16
  const int bb = blk >> 3, eg = blk & 7;
  short8_t epv[4][2];
  #pragma unroll
  for (int r = 0; r < 4; ++r) {
    const u16* p = encp + ((size_t)(bb * 64 + wid * 4 + r)) * H_ + lane * 16;
    epv[r][0] = *(const short8_t*)(p);     KEEPV(epv[r][0]);
    epv[r][1] = *(const short8_t*)(p + 8); KEEPV(epv[r][1]);
  }
  short8_t wlv[2];
  wlv[0] = *(const short8_t*)(wlb + lane * 16);     KEEPV(wlv[0]);
  wlv[1] = *(const short8_t*)(wlb + lane * 16 + 8); KEEPV(wlv[1]);
  // ctx: 4 threads per e-col, each covers 16 si
  const int eloc = t >> 2, quarter = t & 3;
  const int ecol = eg * 256 + eloc;
  short8_t et[2];
  #pragma unroll
  for (int i = 0; i < 2; ++i) {
    et[i] = *(const short8_t*)(encT + (size_t)ecol * 2048 + bb * 64 + quarter * 16 + i * 8);
    KEEPV(et[i]);
  }

  // finalizer-thread constants + fp32 state in registers (writer == reader)
  const int pc4 = blk * 8 + l15, jcol = pc4 >> 1, isc = pc4 & 1;
  const int rb = wid * 16 + l4 * 4;
  const bool fin = (wid < 2) && (l15 < 8);
  float sreg[4] = {0.f, 0.f, 0.f, 0.f};

  // P0: init Xs[0] + register state
  {
    int idx = blk * 1024 + t;
    u16* xs0h = xs_hi(w, 0);
    u16* xs0l = xs0h + B_ * H_;
    if (idx < B_ * H_) {
      float v = prev_s[idx];
      u16 h = f2bf(v);
      st_u16(&xs0h[idx], h);
      st_u16(&xs0l[idx], f2bf(v - bf2f(h)));
    }
    if (fin) {
      #pragma unroll
      for (int r = 0; r < 4; ++r) sreg[r] = prev_s[(rb + r) * H_ + jcol];
    }
  }
  gridbar(bar, ++ep);

  for (int ts = 0; ts < T_; ++ts) {
    const u16* xsh = xs_hi(w, ts);
    const u16* xsl = xsh + B_ * H_;
    u16* xch = xc_hi(w, ts);
    u16* xcl = xch + B_ * H2_;
    float* qfv = qf_v(w, ts);

    // prefetch xg for the gate epilogue (hides under P1/P2)
    float xv[4] = {0.f, 0.f, 0.f, 0.f};
    if (fin) {
      const float* xg = isc ? xg2 : xgr;
      #pragma unroll
      for (int r = 0; r < 4; ++r)
        xv[r] = xg[((size_t)ts * B_ + rb + r) * H_ + jcol];
    }

    // ---- P1: q = s @ Wprev (full-K per block; blocks 0..63) ----
    if (blk < 64) {
      f32x4 aA = {}, aB = {};
      #pragma unroll
      for (int i = 0; i < 2; ++i) {
        int kof = (wid * 2 + i) * 32 + klo;
        short8_t avA = *(const short8_t*)(xsh + l15 * H_ + kof);
        short8_t avB = *(const short8_t*)(xsh + (l15 + 16) * H_ + kof);
        aA = MFMA16(avA, wq[i], aA);
        aB = MFMA16(avB, wq[i], aB);
      }
      scr[(wid * 2 + 0) * 64 + lane] = aA;
      scr[(wid * 2 + 1) * 64 + lane] = aB;
      __syncthreads();
      if (wid < 2) {
        f32x4 s = scr[wid * 64 + lane];
        #pragma unroll
        for (int i = 1; i < 16; ++i) s += scr[(i * 2 + wid) * 64 + lane];
        int col = gq * 16 + l15;
        #pragma unroll
        for (int r = 0; r < 4; ++r)
          st_f32(&qfv[(size_t)(rb + r) * H_ + col], s[r]);
      }
    }
    gridbar(bar, ++ep);

    // ---- P2: scores (8-way redundant per b) + softmax + ctx ----
    {
      float qv[16];
      #pragma unroll
      for (int i = 0; i < 4; ++i) {
        float4 s0 = *(const float4*)(qfv + (size_t)bb * H_ + lane * 16 + i * 4);
        qv[i * 4 + 0] = s0.x; qv[i * 4 + 1] = s0.y;
        qv[i * 4 + 2] = s0.z; qv[i * 4 + 3] = s0.w;
      }
      #pragma unroll
      for (int r = 0; r < 4; ++r) {
        float p = 0.f;
        #pragma unroll
        for (int jj = 0; jj < 16; ++jj)
          p += ftanh(bf2f((u16)epv[r][jj >> 3][jj & 7]) + qv[jj]) * bf2f((u16)wlv[jj >> 3][jj & 7]);
        #pragma unroll
        for (int off = 32; off; off >>= 1) p += __shfl_xor(p, off, 64);
        if (lane == 0) sc[wid * 4 + r] = p;
      }
      __syncthreads();
      if (wid == 0) {
        float v = sc[lane];
        float m = v;
        #pragma unroll
        for (int off = 32; off; off >>= 1) m = fmaxf(m, __shfl_xor(m, off, 64));
        float e = __expf(v - m);
        float s = e;
        #pragma unroll
        for (int off = 32; off; off >>= 1) s += __shfl_xor(s, off, 64);
        sc[lane] = e * frcp(s);
      }
      __syncthreads();
      {
        float a = 0.f;
        #pragma unroll
        for (int i = 0; i < 2; ++i)
          #pragma unroll
          for (int j = 0; j < 8; ++j)
            a += sc[quarter * 16 + i * 8 + j] * bf2f((u16)et[i][j]);
        a += __shfl_xor(a, 1, 64);
        a += __shfl_xor(a, 2, 64);
        if (quarter == 0) {
          u16 hh = f2bf(a);
          st_u16(&xch[bb * H2_ + ecol], hh);
          st_u16(&xcl[bb * H2_ + ecol], f2bf(a - bf2f(hh)));
        }
      }
    }
    gridbar(bar, ++ep);

    // ---- P3: gates ([s|ctx] @ Wcat split-bf16, B from LDS) + state update ----
    {
      f32x4 aA = {}, aB = {};
      #pragma unroll
      for (int i = 0; i < 6; ++i) {
        int kb = wid * 6 + i;
        int k = kb * 32 + klo;
        const u16 *ah, *al; int rs;
        if (kb < 32) { ah = xsh + l15 * H_ + k;          al = xsl + l15 * H_ + k;          rs = H_;  }
        else         { ah = xch + l15 * H2_ + (k - H_);  al = xcl + l15 * H2_ + (k - H_);  rs = H2_; }
        short8_t hA = *(const short8_t*)ah;
        short8_t lA = *(const short8_t*)al;
        short8_t hB = *(const short8_t*)(ah + 16 * rs);
        short8_t lB = *(const short8_t*)(al + 16 * rs);
        short8_t bv = wg_lds[kb * 64 + lane];
        aA = MFMA16(hA, bv, aA);
        aA = MFMA16(lA, bv, aA);
        aB = MFMA16(hB, bv, aB);
        aB = MFMA16(lB, bv, aB);
      }
      scr[(wid * 2 + 0) * 64 + lane] = aA;
      scr[(wid * 2 + 1) * 64 + lane] = aB;
      __syncthreads();
      if (wid < 2) {
        f32x4 s = scr[wid * 64 + lane];
        #pragma unroll
        for (int i = 1; i < 16; ++i) s += scr[(i * 2 + wid) * 64 + lane];
        float tot[4];
        #pragma unroll
        for (int r = 0; r < 4; ++r) tot[r] = s[r] + __shfl_xor(s[r], 8, 64);
        if (l15 < 8) {
          u16* nsh = xs_hi(w, ts + 1);
          u16* nsl = nsh + B_ * H_;
          #pragma unroll
          for (int r = 0; r < 4; ++r) {
            int brow = rb + r;
            float pre = tot[r] + xv[r];
            float mate = __shfl_xor(pre, 1, 64);
            float rpre = isc ? mate : pre;
            float cpre = isc ? pre : mate;
            float rg = fsigm(rpre);
            float cg = ftanh(cpre);
            float sp = sreg[r];
            float sn = sp + rg * (cg - sp);
            sreg[r] = sn;
            if (!isc) {
              u16 hh = f2bf(sn);
              st_u16(&nsh[brow * H_ + jcol], hh);
              st_u16(&nsl[brow * H_ + jcol], f2bf(sn - bf2f(hh)));
              dech[((size_t)brow * T_ + ts) * H_ + jcol] = hh;
              if (ts == T_ - 1) fout[brow * H_ + jcol] = sn;
            }
          }
        }
      }
    }
    gridbar(bar, ++ep);
  }
}

// ---------------- host ----------------

extern "C" void kernel_launch(void* const* d_in, const int* in_sizes, int n_in,
                              void* d_out, int out_size, void* d_ws, size_t ws_size,
                              hipStream_t stream) {
  const float* enc_h    = (const float*)d_in[0];
  const float* prev_s   = (const float*)d_in[1];
  const int*   target   = (const int*)d_in[2];
  const float* embed    = (const float*)d_in[3];
  const float* att_Wenc = (const float*)d_in[4];
  const float* att_benc = (const float*)d_in[5];
  const float* att_Wprev= (const float*)d_in[6];
  const float* att_bprev= (const float*)d_in[7];
  const float* att_wlin = (const float*)d_in[8];
  const float* dc_Wi    = (const float*)d_in[10];
  const float* dc_bi    = (const float*)d_in[11];
  const float* dc_Wh    = (const float*)d_in[12];
  const float* dc_bh    = (const float*)d_in[13];
  const float* dc_Wc    = (const float*)d_in[14];
  const float* dc_bc    = (const float*)d_in[15];
  const float* dc_Wi2   = (const float*)d_in[16];
  const float* dc_bi2   = (const float*)d_in[17];
  const float* dc_Wh2   = (const float*)d_in[18];
  const float* dc_bh2   = (const float*)d_in[19];
  const float* dc_Wc2   = (const float*)d_in[20];
  const float* dc_bc2   = (const float*)d_in[21];
  const float* out_W    = (const float*)d_in[22];
  const float* out_b    = (const float*)d_in[23];

  char* w = (char*)d_ws;
  float* x    = (float*)(w + X_OFF);
  float* xgr  = (float*)(w + XGR_OFF);
  float* xg2  = (float*)(w + XG2_OFF);
  u16*  encp  = (u16*)(w + X_OFF);       // aliases x (after xgr/xg2 gemms)
  u16*  encT  = (u16*)(w + ENCT_OFF);
  u16*  wqf   = (u16*)(w + WQF_OFF);
  u16*  wgf   = (u16*)(w + WGF_OFF);
  u16*  wot   = (u16*)(w + WOT_OFF);     // aliases pool (after mega)
  u16*  dech  = (u16*)(w + DECH_OFF);
  float* bas  = (float*)(w + BAS_OFF);
  float* bcr  = (float*)(w + BCR_OFF);
  float* bc2  = (float*)(w + BC2_OFF);
  u16*  wlb   = (u16*)(w + WLB_OFF);
  int*  bar   = (int*)(w + BAR_OFF);
  float* fout = (float*)d_out + (size_t)BT_ * V_;

  hipMemsetAsync(bar, 0, 4096, stream);

  // prologue
  k_gather  <<<BT_, 128, 0, stream>>>(x, embed, target);
  k_biascomb<<<4, 256, 0, stream>>>(bcr, bc2, bas, wlb,
                                    dc_bi, dc_bh, dc_bc, dc_bi2, dc_bh2, dc_bc2,
                                    att_benc, att_bprev, att_wlin);
  k_gemm<<<16 * 8, 256, 0, stream>>>(x, E_, dc_Wi,  H2_, xgr, H_, 0, bcr, 16, 8, E_);
  k_gemm<<<16 * 8, 256, 0, stream>>>(x, E_, dc_Wi2, H_,  xg2, H_, 0, bc2, 16, 8, E_);
  k_gemm<<<16 * 8, 256, 0, stream>>>(enc_h, H2_, att_Wenc, H_, encp, H_, 1, bas, 16, 8, H2_);
  k_transE<<<1024, 256, 0, stream>>>(encT, enc_h);
  k_packq <<<512, 256, 0, stream>>>(wqf, att_Wprev);
  k_packg <<<3072, 256, 0, stream>>>(wgf, dc_Wh, dc_Wc, dc_Wh2, dc_Wc2);

  // the 64-step recurrence: versioned buffers + relaxed barriers, 16 waves/CU
  k_mega<<<256, 1024, 0, stream>>>(w, dech, fout,
                                   wqf, wgf, encp, encT, xgr, xg2,
                                   prev_s, wlb, bar);

  // vocab projection in two halves (wot aliases dead prologue workspace)
  k_wtrans<<<4000, 256, 0, stream>>>(wot, out_W, 0);
  k_gemm2 <<<2000, 256, 0, stream>>>(dech, wot, (float*)d_out, out_b, 0);
  k_wtrans<<<4000, 256, 0, stream>>>(wot, out_W, 16000);
  k_gemm2 <<<2000, 256, 0, stream>>>(dech, wot, (float*)d_out, out_b, 16000);
}

// Round 7
// 3187.549 us; speedup vs baseline: 1.2883x; 1.2883x over previous
//
#include <hip/hip_runtime.h>

// Sizes
#define B_   32
#define S_   64
#define T_   64
#define H_   1024
#define H2_  2048
#define E_   512
#define V_   32000
#define K3_  3072
#define BT_  2048

typedef unsigned short u16;
typedef __attribute__((ext_vector_type(8))) short short8_t;  // 8 x bf16
typedef __attribute__((ext_vector_type(4))) float f32x4;

__device__ __forceinline__ u16 f2bf(float f) {
  unsigned x = __float_as_uint(f);
  unsigned r = (x + 0x7fffu + ((x >> 16) & 1u)) >> 16;  // RNE
  return (u16)r;
}
__device__ __forceinline__ float bf2f(u16 h) {
  return __uint_as_float(((unsigned)h) << 16);
}
__device__ __forceinline__ float frcp(float x) { return __builtin_amdgcn_rcpf(x); }
__device__ __forceinline__ float ftanh(float x) {
  float e = __expf(2.f * x);
  return 1.f - 2.f * frcp(e + 1.f);
}
__device__ __forceinline__ float fsigm(float x) {
  return frcp(1.f + __expf(-x));
}

// pin a loaded value in VGPRs: opaque asm result cannot be rematerialized
#define KEEPV(x) asm volatile("" : "+v"(x))

// write-through to the coherent point (LLC) — visible cross-XCD, no fence
__device__ __forceinline__ void st_u16(u16* p, u16 v) {
  __hip_atomic_store(p, v, __ATOMIC_RELAXED, __HIP_MEMORY_SCOPE_AGENT);
}
__device__ __forceinline__ void st_f32(float* p, float v) {
  __hip_atomic_store(p, v, __ATOMIC_RELAXED, __HIP_MEMORY_SCOPE_AGENT);
}

// ---------------- workspace layout (bytes) ----------------
#define MB_ (1ull << 20)
#define KB_ (1ull << 10)
#define X_OFF    (0)              // 4MB; encp aliases after xgr/xg2 gemms
#define XGR_OFF  (4*MB_)          // 8MB
#define XG2_OFF  (12*MB_)         // 8MB
#define ENCT_OFF (20*MB_)         // 8MB (pre-loop only)
#define QFV_OFF  (20*MB_)         // qf versions t=0..63 x 128KB (aliases encT)
#define WQF_OFF  (28*MB_)         // 2MB (pre-loop only)
#define WGF_OFF  (30*MB_)         // 24MB (pre-loop only)
#define XSV_OFF  (28*MB_)         // Xs versions t=1..64 x 128KB -> [28,36)
#define XCV_OFF  (36*MB_)         // Xc versions t=0..63 x 256KB -> [36,52)
#define WOT_OFF  (0)              // 32MB (after mega only)
#define DECH_OFF (54*MB_)         // 4MB
#define XS0_OFF  (58*MB_)         // 128KB (Xs version 0, written pre-barrier)
#define BAS_OFF  (58*MB_ + 128*KB_)   // 4KB
#define BCR_OFF  (58*MB_ + 132*KB_)   // 4KB
#define BC2_OFF  (58*MB_ + 136*KB_)   // 4KB
#define WLB_OFF  (58*MB_ + 140*KB_)   // 2KB
#define BAR_OFF  (58*MB_ + 144*KB_)   // 8KB

// version-buffer address helpers
__device__ __forceinline__ u16* xs_hi(char* w, int t) {
  return (u16*)(t == 0 ? (w + XS0_OFF) : (w + XSV_OFF + (size_t)(t - 1) * 131072));
}
__device__ __forceinline__ u16* xc_hi(char* w, int t) {
  return (u16*)(w + XCV_OFF + (size_t)t * 262144);
}
__device__ __forceinline__ float* qf_v(char* w, int t) {
  return (float*)(w + QFV_OFF + (size_t)t * 131072);
}

// ---------------- prologue kernels ----------------

__global__ void k_gather(float* __restrict__ x, const float* __restrict__ embed,
                         const int* __restrict__ tgt) {
  int bid = blockIdx.x;              // t*B + b
  int t = bid >> 5, b = bid & 31;
  int row = tgt[b * T_ + t];
  const float4* src = (const float4*)(embed + (size_t)row * E_);
  float4* dst = (float4*)(x + (size_t)bid * E_);
  dst[threadIdx.x] = src[threadIdx.x];
}

__global__ void k_biascomb(float* bcr, float* bc2o, float* bas, u16* wlb,
                           const float* bi, const float* bh, const float* bc,
                           const float* bi2, const float* bh2, const float* bc2i,
                           const float* benc, const float* bprev, const float* wlin) {
  int j = blockIdx.x * 256 + threadIdx.x;
  if (j < H_) {
    bcr[j]  = bi[j]  + bh[j]  + bc[j];
    bc2o[j] = bi2[j] + bh2[j] + bc2i[j];
    bas[j]  = benc[j] + bprev[j];
    wlb[j]  = f2bf(wlin[j]);
  }
}

// generic 128x128 bf16-MFMA GEMM (fp32 in, fp32/bf16 out) — prologue only
__global__ __launch_bounds__(256) void k_gemm(
    const float* __restrict__ A, int lda,
    const float* __restrict__ Bm, int ldb,
    void* __restrict__ Cv, int ldc, int outBf16,
    const float* __restrict__ bias,
    int mtiles, int ntiles, int K) {
  __shared__ u16 As[128][72];
  __shared__ u16 Bs[128][72];
  int nwg = mtiles * ntiles;
  int bid = blockIdx.x;
  int cpx = nwg >> 3;
  int lb = (bid & 7) * cpx + (bid >> 3);
  int ntb = lb / mtiles, mtb = lb - ntb * mtiles;
  size_t m0 = (size_t)mtb * 128, n0 = (size_t)ntb * 128;
  int t = threadIdx.x, lane = t & 63, wid = t >> 6;
  int wr = (wid >> 1) * 64, wc = (wid & 1) * 64;
  f32x4 acc[4][4] = {};
  for (int k0 = 0; k0 < K; k0 += 64) {
    #pragma unroll
    for (int i = 0; i < 8; ++i) {
      int f4 = i * 256 + t;
      int row = f4 >> 4, c4 = (f4 & 15) << 2;
      float4 v = *(const float4*)(A + (m0 + row) * (size_t)lda + k0 + c4);
      ushort4 u; u.x = f2bf(v.x); u.y = f2bf(v.y); u.z = f2bf(v.z); u.w = f2bf(v.w);
      *(ushort4*)&As[row][c4] = u;
    }
    #pragma unroll
    for (int i = 0; i < 8; ++i) {
      int f4 = i * 256 + t;
      int kr = f4 >> 5, c4 = (f4 & 31) << 2;
      float4 v = *(const float4*)(Bm + (size_t)(k0 + kr) * ldb + n0 + c4);
      Bs[c4 + 0][kr] = f2bf(v.x);
      Bs[c4 + 1][kr] = f2bf(v.y);
      Bs[c4 + 2][kr] = f2bf(v.z);
      Bs[c4 + 3][kr] = f2bf(v.w);
    }
    __syncthreads();
    #pragma unroll
    for (int kk = 0; kk < 64; kk += 32) {
      int ko = kk + (lane >> 4) * 8;
      short8_t am[4], bn[4];
      #pragma unroll
      for (int m = 0; m < 4; ++m) am[m] = *(const short8_t*)&As[wr + m * 16 + (lane & 15)][ko];
      #pragma unroll
      for (int n = 0; n < 4; ++n) bn[n] = *(const short8_t*)&Bs[wc + n * 16 + (lane & 15)][ko];
      #pragma unroll
      for (int m = 0; m < 4; ++m)
        #pragma unroll
        for (int n = 0; n < 4; ++n)
          acc[m][n] = __builtin_amdgcn_mfma_f32_16x16x32_bf16(am[m], bn[n], acc[m][n], 0, 0, 0);
    }
    __syncthreads();
  }
  #pragma unroll
  for (int n = 0; n < 4; ++n) {
    int col = wc + n * 16 + (lane & 15);
    float bv = bias ? bias[n0 + col] : 0.f;
    #pragma unroll
    for (int m = 0; m < 4; ++m) {
      size_t row = m0 + wr + m * 16 + ((lane >> 4) << 2);
      #pragma unroll
      for (int r = 0; r < 4; ++r) {
        float val = acc[m][n][r] + bv;
        if (outBf16) ((u16*)Cv)[(row + r) * (size_t)ldc + n0 + col] = f2bf(val);
        else ((float*)Cv)[(row + r) * (size_t)ldc + n0 + col] = val;
      }
    }
  }
}

// enc_h -> encT[e][b*64+si] bf16
__global__ __launch_bounds__(256) void k_transE(u16* __restrict__ encT,
                                                const float* __restrict__ enc_h) {
  __shared__ u16 ld[64][68];
  int b = blockIdx.x >> 5, et = blockIdx.x & 31;
  int e0 = et * 64;
  int t = threadIdx.x;
  #pragma unroll
  for (int i = 0; i < 4; ++i) {
    int f4 = i * 256 + t;
    int si = f4 >> 4, e4 = (f4 & 15) << 2;
    float4 v = *(const float4*)(enc_h + ((size_t)(b * 64 + si)) * H2_ + e0 + e4);
    ld[si][e4 + 0] = f2bf(v.x); ld[si][e4 + 1] = f2bf(v.y);
    ld[si][e4 + 2] = f2bf(v.z); ld[si][e4 + 3] = f2bf(v.w);
  }
  __syncthreads();
  #pragma unroll
  for (int i = 0; i < 2; ++i) {
    int idx = i * 256 + t;
    int e = idx >> 3, s8 = (idx & 7) << 3;
    short8_t o;
    #pragma unroll
    for (int k = 0; k < 8; ++k) o[k] = (short)ld[s8 + k][e];
    *(short8_t*)(encT + ((size_t)(e0 + e)) * 2048 + b * 64 + s8) = o;
  }
}

// att_Wprev -> wqf frag-major bf16 (LDS-tiled, coalesced source reads)
__global__ __launch_bounds__(256) void k_packq(u16* __restrict__ wqf,
                                               const float* __restrict__ W) {
  __shared__ float ld[64][33];
  int jt = blockIdx.x & 31, kt = blockIdx.x >> 5;   // 32 x 16
  int c0 = jt * 32, k0 = kt * 64;
  int t = threadIdx.x;
  #pragma unroll
  for (int i = 0; i < 8; ++i) {
    int idx = i * 256 + t; int kr = idx >> 5, jc = idx & 31;
    ld[kr][jc] = W[(size_t)(k0 + kr) * H_ + c0 + jc];
  }
  __syncthreads();
  int u = t;
  int gl = u >> 7, kbl = (u >> 6) & 1, sub = (u >> 4) & 3, c = u & 15;
  int colLoc = gl * 16 + c;
  int gG = jt * 2 + gl, KB = kt * 2 + kbl;
  size_t lin = ((size_t)(gG * 32 + KB) * 4 + sub) * 16 + c;
  short8_t o;
  #pragma unroll
  for (int j = 0; j < 8; ++j) o[j] = (short)f2bf(ld[kbl * 32 + sub * 8 + j][colLoc]);
  *(short8_t*)(wqf + lin * 8) = o;
}

// gate weights -> wgf frag-major (hi in c<8, lo in c>=8), LDS-tiled
__global__ __launch_bounds__(256) void k_packg(
    u16* __restrict__ wgf, const float* __restrict__ Wh, const float* __restrict__ Wc,
    const float* __restrict__ Wh2, const float* __restrict__ Wc2) {
  __shared__ float ld[64][33];
  int sel = blockIdx.x & 1;
  int jt  = (blockIdx.x >> 1) & 31;
  int kt  = blockIdx.x >> 6;          // 0..47
  int k0 = kt * 64, j0 = jt * 32;
  int t = threadIdx.x;
  const float* srcW = (k0 < H_) ? (sel ? Wh2 : Wh) : (sel ? Wc2 : Wc);
  int ldw = sel ? H_ : H2_;
  int koff = (k0 < H_) ? k0 : (k0 - H_);
  #pragma unroll
  for (int i = 0; i < 8; ++i) {
    int idx = i * 256 + t; int kr = idx >> 5, jc = idx & 31;
    ld[kr][jc] = srcW[(size_t)(koff + kr) * ldw + j0 + jc];
  }
  __syncthreads();
  #pragma unroll
  for (int it = 0; it < 2; ++it) {
    int u = it * 256 + t;
    int m = u & 3, sub = (u >> 2) & 3, kbl = (u >> 4) & 1, islo = (u >> 5) & 1, gg = u >> 6;
    int jjLoc = gg * 4 + m;
    int p = 2 * (j0 + jjLoc) + sel;
    int g = p >> 3, cc = p & 7;
    int c = cc + 8 * islo;
    int KB = kt * 2 + kbl;
    size_t lin = ((size_t)(g * 96 + KB) * 4 + sub) * 16 + c;
    short8_t o;
    #pragma unroll
    for (int j = 0; j < 8; ++j) {
      float v = ld[kbl * 32 + sub * 8 + j][jjLoc];
      u16 h = f2bf(v);
      o[j] = (short)(islo ? f2bf(v - bf2f(h)) : h);
    }
    *(short8_t*)(wgf + lin * 8) = o;
  }
}

// out_W half -> wot bf16 [nLocal 16000][k 1024]
__global__ __launch_bounds__(256) void k_wtrans(u16* __restrict__ wot,
                                                const float* __restrict__ W, int nbase) {
  __shared__ u16 ld[64][68];
  int nt = blockIdx.x % 250, kt = blockIdx.x / 250;
  int n0 = nbase + nt * 64, k0 = kt * 64;
  int t = threadIdx.x;
  #pragma unroll
  for (int i = 0; i < 4; ++i) {
    int f4 = i * 256 + t;
    int kr = f4 >> 4, n4 = (f4 & 15) << 2;
    float4 v = *(const float4*)(W + (size_t)(k0 + kr) * V_ + n0 + n4);
    ld[kr][n4 + 0] = f2bf(v.x); ld[kr][n4 + 1] = f2bf(v.y);
    ld[kr][n4 + 2] = f2bf(v.z); ld[kr][n4 + 3] = f2bf(v.w);
  }
  __syncthreads();
  #pragma unroll
  for (int i = 0; i < 2; ++i) {
    int idx = i * 256 + t;
    int n = idx >> 3, k8 = (idx & 7) << 3;
    short8_t o;
    #pragma unroll
    for (int k = 0; k < 8; ++k) o[k] = (short)ld[k8 + k][n];
    *(short8_t*)(wot + ((size_t)(nt * 64 + n)) * H_ + k0 + k8) = o;
  }
}

// final GEMM: dech bf16 [2048][1024] @ wot^T -> C fp32 (per 16000-col half)
__global__ __launch_bounds__(256) void k_gemm2(
    const u16* __restrict__ A, const u16* __restrict__ Bt,
    float* __restrict__ C, const float* __restrict__ bias, int n0g) {
  __shared__ u16 As[128][72];
  __shared__ u16 Bs[128][72];
  int bid = blockIdx.x;
  int lb = (bid & 7) * 250 + (bid >> 3);
  int mtb = lb & 15, ntb = lb >> 4;
  size_t m0 = (size_t)mtb * 128;
  size_t nl0 = (size_t)ntb * 128;
  int t = threadIdx.x, lane = t & 63, wid = t >> 6;
  int wr = (wid >> 1) * 64, wc = (wid & 1) * 64;
  f32x4 acc[4][4] = {};
  for (int k0 = 0; k0 < H_; k0 += 64) {
    #pragma unroll
    for (int i = 0; i < 4; ++i) {
      int idx = i * 256 + t;
      int row = idx >> 3, c8 = (idx & 7) << 3;
      *(short8_t*)&As[row][c8] = *(const short8_t*)(A + (m0 + row) * H_ + k0 + c8);
      *(short8_t*)&Bs[row][c8] = *(const short8_t*)(Bt + (nl0 + row) * H_ + k0 + c8);
    }
    __syncthreads();
    #pragma unroll
    for (int kk = 0; kk < 64; kk += 32) {
      int ko = kk + (lane >> 4) * 8;
      short8_t am[4], bn[4];
      #pragma unroll
      for (int m = 0; m < 4; ++m) am[m] = *(const short8_t*)&As[wr + m * 16 + (lane & 15)][ko];
      #pragma unroll
      for (int n = 0; n < 4; ++n) bn[n] = *(const short8_t*)&Bs[wc + n * 16 + (lane & 15)][ko];
      #pragma unroll
      for (int m = 0; m < 4; ++m)
        #pragma unroll
        for (int n = 0; n < 4; ++n)
          acc[m][n] = __builtin_amdgcn_mfma_f32_16x16x32_bf16(am[m], bn[n], acc[m][n], 0, 0, 0);
    }
    __syncthreads();
  }
  #pragma unroll
  for (int n = 0; n < 4; ++n) {
    int col = n0g + (int)nl0 + wc + n * 16 + (lane & 15);
    float bv = bias[col];
    #pragma unroll
    for (int m = 0; m < 4; ++m) {
      size_t row = m0 + wr + m * 16 + ((lane >> 4) << 2);
      #pragma unroll
      for (int r = 0; r < 4; ++r)
        C[(row + r) * (size_t)V_ + col] = acc[m][n][r] + bv;
    }
  }
}

// ---------------- persistent decoder kernel ----------------

// relaxed barrier, leaf-epoch broadcast: root winner publishes the epoch to 32
// per-leaf cache lines; each line is polled by only 8 blocks (less LLC
// contention than 256 pollers on one address). No cache maintenance —
// versioned buffers give freshness.
__device__ __forceinline__ void gridbar(int* bar, int target) {
  asm volatile("s_waitcnt vmcnt(0)" ::: "memory");
  __syncthreads();
  if (threadIdx.x == 0) {
    int* leafcnt = bar;            // 32 x stride-16 ints
    int* root    = bar + 512;
    int* leafep  = bar + 768;      // 32 x stride-16 ints
    int li = blockIdx.x >> 3;
    if (__hip_atomic_fetch_add(&leafcnt[li * 16], 1, __ATOMIC_RELAXED, __HIP_MEMORY_SCOPE_AGENT) == 7) {
      __hip_atomic_store(&leafcnt[li * 16], 0, __ATOMIC_RELAXED, __HIP_MEMORY_SCOPE_AGENT);
      if (__hip_atomic_fetch_add(root, 1, __ATOMIC_RELAXED, __HIP_MEMORY_SCOPE_AGENT) == 31) {
        __hip_atomic_store(root, 0, __ATOMIC_RELAXED, __HIP_MEMORY_SCOPE_AGENT);
        #pragma unroll
        for (int i = 0; i < 32; ++i)
          __hip_atomic_store(&leafep[i * 16], target, __ATOMIC_RELAXED, __HIP_MEMORY_SCOPE_AGENT);
      }
    }
    while (__hip_atomic_load(&leafep[li * 16], __ATOMIC_RELAXED, __HIP_MEMORY_SCOPE_AGENT) != target)
      __builtin_amdgcn_s_sleep(2);
  }
  __syncthreads();
}

#define MFMA16(a, b, c) __builtin_amdgcn_mfma_f32_16x16x32_bf16((a), (b), (c), 0, 0, 0)

// 512 threads, min-waves 1: LDS (112KB) pins 1 block/CU, so VGPRs are free to
// grow to ~256 — used for cross-barrier prefetch of P3's Xs operands.
__global__ __launch_bounds__(512, 1) void k_mega(
    char* w, u16* __restrict__ dech, float* __restrict__ fout,
    const u16* __restrict__ wqf, const u16* __restrict__ wgf,
    const u16* __restrict__ encp, const u16* __restrict__ encT,
    const float* __restrict__ xgr, const float* __restrict__ xg2,
    const float* __restrict__ prev_s, const u16* __restrict__ wlb,
    int* bar) {
  const int t = threadIdx.x, blk = blockIdx.x;
  const int lane = t & 63, wid = t >> 6;
  const int l15 = lane & 15, l4 = lane >> 4;
  const int klo = l4 * 8;
  __shared__ short8_t wg_lds[6144];   // 96KB — gate weights, LDS-resident
  __shared__ f32x4 scr[1024];         // 16KB reduce scratch
  __shared__ float sc[64];
  int ep = 0;

  // LDS-resident gate-weight slice (per block), loaded ONCE (pre-loop only)
  for (int i = t; i < 6144; i += 512)
    wg_lds[i] = *(const short8_t*)(wgf + ((size_t)blk * 6144 + i) * 8);

  // ---- register-resident operands, loaded ONCE and pinned (KEEPV) ----
  const int gq = blk & 63;
  short8_t wq[4];
  #pragma unroll
  for (int i = 0; i < 4; ++i) {
    wq[i] = *(const short8_t*)(wqf + ((size_t)(gq * 32 + wid * 4 + i) * 64 + lane) * 8);
    KEEPV(wq[i]);
  }
  const int bb = blk >> 3, eg = blk & 7;
  short8_t epv[8][2];
  #pragma unroll
  for (int r = 0; r < 8; ++r) {
    const u16* p = encp + ((size_t)(bb * 64 + wid * 8 + r)) * H_ + lane * 16;
    epv[r][0] = *(const short8_t*)(p);     KEEPV(epv[r][0]);
    epv[r][1] = *(const short8_t*)(p + 8); KEEPV(epv[r][1]);
  }
  short8_t wlv[2];
  wlv[0] = *(const short8_t*)(wlb + lane * 16);     KEEPV(wlv[0]);
  wlv[1] = *(const short8_t*)(wlb + lane * 16 + 8); KEEPV(wlv[1]);
  const int eloc = t >> 1, half = t & 1;
  const int ecol = eg * 256 + eloc;
  short8_t et[4];
  #pragma unroll
  for (int i = 0; i < 4; ++i) {
    et[i] = *(const short8_t*)(encT + (size_t)ecol * 2048 + bb * 64 + half * 32 + i * 8);
    KEEPV(et[i]);
  }

  // finalizer-thread constants + fp32 state in registers (writer == reader)
  const int pc4 = blk * 8 + l15, jcol = pc4 >> 1, isc = pc4 & 1;
  const int rb = wid * 16 + l4 * 4;
  const bool fin = (wid < 2) && (l15 < 8);
  float sreg[4] = {0.f, 0.f, 0.f, 0.f};

  // P0: init Xs[0] + register state
  {
    int idx = blk * 512 + t;
    u16* xs0h = xs_hi(w, 0);
    u16* xs0l = xs0h + B_ * H_;
    if (idx < B_ * H_) {
      float v = prev_s[idx];
      u16 h = f2bf(v);
      st_u16(&xs0h[idx], h);
      st_u16(&xs0l[idx], f2bf(v - bf2f(h)));
    }
    if (fin) {
      #pragma unroll
      for (int r = 0; r < 4; ++r) sreg[r] = prev_s[(rb + r) * H_ + jcol];
    }
  }
  gridbar(bar, ++ep);

  for (int ts = 0; ts < T_; ++ts) {
    const u16* xsh = xs_hi(w, ts);
    const u16* xsl = xsh + B_ * H_;
    u16* xch = xc_hi(w, ts);
    u16* xcl = xch + B_ * H2_;
    float* qfv = qf_v(w, ts);

    // ---- step-top prefetches: valid as soon as the prev-step barrier passed.
    // (a) xg operands for the gate epilogue
    float xv[4] = {0.f, 0.f, 0.f, 0.f};
    if (fin) {
      const float* xg = isc ? xg2 : xgr;
      #pragma unroll
      for (int r = 0; r < 4; ++r)
        xv[r] = xg[((size_t)ts * B_ + rb + r) * H_ + jcol];
    }
    // (b) P3's Xs-half A-operands (hi part): kb = wid + 8*i, i<4 — their LLC
    // round-trip overlaps P1+P2 instead of sitting on P3's critical path.
    short8_t pA[4], pB[4];
    #pragma unroll
    for (int i = 0; i < 4; ++i) {
      int k = (wid + 8 * i) * 32 + klo;
      pA[i] = *(const short8_t*)(xsh + l15 * H_ + k);        KEEPV(pA[i]);
      pB[i] = *(const short8_t*)(xsh + (l15 + 16) * H_ + k); KEEPV(pB[i]);
    }

    // ---- P1: q = s @ Wprev (full-K per block; blocks 0..63) ----
    if (blk < 64) {
      f32x4 aA = {}, aB = {};
      #pragma unroll
      for (int i = 0; i < 4; ++i) {
        int kof = (wid * 4 + i) * 32 + klo;
        short8_t avA = *(const short8_t*)(xsh + l15 * H_ + kof);
        short8_t avB = *(const short8_t*)(xsh + (l15 + 16) * H_ + kof);
        aA = MFMA16(avA, wq[i], aA);
        aB = MFMA16(avB, wq[i], aB);
      }
      scr[(wid * 2 + 0) * 64 + lane] = aA;
      scr[(wid * 2 + 1) * 64 + lane] = aB;
      __syncthreads();
      if (wid < 2) {
        f32x4 s = scr[wid * 64 + lane];
        #pragma unroll
        for (int i = 1; i < 8; ++i) s += scr[(i * 2 + wid) * 64 + lane];
        int col = gq * 16 + l15;
        #pragma unroll
        for (int r = 0; r < 4; ++r)
          st_f32(&qfv[(size_t)(rb + r) * H_ + col], s[r]);
      }
    }
    gridbar(bar, ++ep);

    // ---- P2: scores (8-way redundant per b) + softmax + ctx ----
    {
      float qv[16];
      #pragma unroll
      for (int i = 0; i < 4; ++i) {
        float4 s0 = *(const float4*)(qfv + (size_t)bb * H_ + lane * 16 + i * 4);
        qv[i * 4 + 0] = s0.x; qv[i * 4 + 1] = s0.y;
        qv[i * 4 + 2] = s0.z; qv[i * 4 + 3] = s0.w;
      }
      #pragma unroll
      for (int r = 0; r < 8; ++r) {
        float p = 0.f;
        #pragma unroll
        for (int jj = 0; jj < 16; ++jj)
          p += ftanh(bf2f((u16)epv[r][jj >> 3][jj & 7]) + qv[jj]) * bf2f((u16)wlv[jj >> 3][jj & 7]);
        #pragma unroll
        for (int off = 32; off; off >>= 1) p += __shfl_xor(p, off, 64);
        if (lane == 0) sc[wid * 8 + r] = p;
      }
      __syncthreads();
      if (wid == 0) {
        float v = sc[lane];
        float m = v;
        #pragma unroll
        for (int off = 32; off; off >>= 1) m = fmaxf(m, __shfl_xor(m, off, 64));
        float e = __expf(v - m);
        float s = e;
        #pragma unroll
        for (int off = 32; off; off >>= 1) s += __shfl_xor(s, off, 64);
        sc[lane] = e * frcp(s);
      }
      __syncthreads();
      {
        float a = 0.f;
        #pragma unroll
        for (int i = 0; i < 4; ++i)
          #pragma unroll
          for (int j = 0; j < 8; ++j)
            a += sc[half * 32 + i * 8 + j] * bf2f((u16)et[i][j]);
        a += __shfl_xor(a, 1, 64);
        if (half == 0) {
          u16 hh = f2bf(a);
          st_u16(&xch[bb * H2_ + ecol], hh);
          st_u16(&xcl[bb * H2_ + ecol], f2bf(a - bf2f(hh)));
        }
      }
    }
    gridbar(bar, ++ep);

    // ---- P3: gates ([s|ctx] @ Wcat split-bf16, B from LDS) + state update ----
    // kb = wid + 8*i: i<4 -> Xs (hi prefetched), i>=4 -> Xc.
    {
      f32x4 aA = {}, aB = {};
      // Xs-lo loads issued first so they overlap the hi MFMAs
      short8_t loA[4], loB[4];
      #pragma unroll
      for (int i = 0; i < 4; ++i) {
        int k = (wid + 8 * i) * 32 + klo;
        loA[i] = *(const short8_t*)(xsl + l15 * H_ + k);
        loB[i] = *(const short8_t*)(xsl + (l15 + 16) * H_ + k);
      }
      #pragma unroll
      for (int i = 0; i < 4; ++i) {
        short8_t bv = wg_lds[(wid + 8 * i) * 64 + lane];
        aA = MFMA16(pA[i], bv, aA);
        aB = MFMA16(pB[i], bv, aB);
      }
      #pragma unroll
      for (int i = 0; i < 4; ++i) {
        short8_t bv = wg_lds[(wid + 8 * i) * 64 + lane];
        aA = MFMA16(loA[i], bv, aA);
        aB = MFMA16(loB[i], bv, aB);
      }
      #pragma unroll
      for (int i = 4; i < 12; ++i) {
        int kb = wid + 8 * i;
        int k = kb * 32 + klo - H_;
        short8_t hA = *(const short8_t*)(xch + l15 * H2_ + k);
        short8_t lA = *(const short8_t*)(xcl + l15 * H2_ + k);
        short8_t hB = *(const short8_t*)(xch + (l15 + 16) * H2_ + k);
        short8_t lB = *(const short8_t*)(xcl + (l15 + 16) * H2_ + k);
        short8_t bv = wg_lds[kb * 64 + lane];
        aA = MFMA16(hA, bv, aA);
        aA = MFMA16(lA, bv, aA);
        aB = MFMA16(hB, bv, aB);
        aB = MFMA16(lB, bv, aB);
      }
      scr[(wid * 2 + 0) * 64 + lane] = aA;
      scr[(wid * 2 + 1) * 64 + lane] = aB;
      __syncthreads();
      if (wid < 2) {
        f32x4 s = scr[wid * 64 + lane];
        #pragma unroll
        for (int i = 1; i < 8; ++i) s += scr[(i * 2 + wid) * 64 + lane];
        float tot[4];
        #pragma unroll
        for (int r = 0; r < 4; ++r) tot[r] = s[r] + __shfl_xor(s[r], 8, 64);
        if (l15 < 8) {
          u16* nsh = xs_hi(w, ts + 1);
          u16* nsl = nsh + B_ * H_;
          #pragma unroll
          for (int r = 0; r < 4; ++r) {
            int brow = rb + r;
            float pre = tot[r] + xv[r];
            float mate = __shfl_xor(pre, 1, 64);
            float rpre = isc ? mate : pre;
            float cpre = isc ? pre : mate;
            float rg = fsigm(rpre);
            float cg = ftanh(cpre);
            float sp = sreg[r];
            float sn = sp + rg * (cg - sp);
            sreg[r] = sn;
            if (!isc) {
              u16 hh = f2bf(sn);
              st_u16(&nsh[brow * H_ + jcol], hh);
              st_u16(&nsl[brow * H_ + jcol], f2bf(sn - bf2f(hh)));
              dech[((size_t)brow * T_ + ts) * H_ + jcol] = hh;
              if (ts == T_ - 1) fout[brow * H_ + jcol] = sn;
            }
          }
        }
      }
    }
    gridbar(bar, ++ep);
  }
}

// ---------------- host ----------------

extern "C" void kernel_launch(void* const* d_in, const int* in_sizes, int n_in,
                              void* d_out, int out_size, void* d_ws, size_t ws_size,
                              hipStream_t stream) {
  const float* enc_h    = (const float*)d_in[0];
  const float* prev_s   = (const float*)d_in[1];
  const int*   target   = (const int*)d_in[2];
  const float* embed    = (const float*)d_in[3];
  const float* att_Wenc = (const float*)d_in[4];
  const float* att_benc = (const float*)d_in[5];
  const float* att_Wprev= (const float*)d_in[6];
  const float* att_bprev= (const float*)d_in[7];
  const float* att_wlin = (const float*)d_in[8];
  const float* dc_Wi    = (const float*)d_in[10];
  const float* dc_bi    = (const float*)d_in[11];
  const float* dc_Wh    = (const float*)d_in[12];
  const float* dc_bh    = (const float*)d_in[13];
  const float* dc_Wc    = (const float*)d_in[14];
  const float* dc_bc    = (const float*)d_in[15];
  const float* dc_Wi2   = (const float*)d_in[16];
  const float* dc_bi2   = (const float*)d_in[17];
  const float* dc_Wh2   = (const float*)d_in[18];
  const float* dc_bh2   = (const float*)d_in[19];
  const float* dc_Wc2   = (const float*)d_in[20];
  const float* dc_bc2   = (const float*)d_in[21];
  const float* out_W    = (const float*)d_in[22];
  const float* out_b    = (const float*)d_in[23];

  char* w = (char*)d_ws;
  float* x    = (float*)(w + X_OFF);
  float* xgr  = (float*)(w + XGR_OFF);
  float* xg2  = (float*)(w + XG2_OFF);
  u16*  encp  = (u16*)(w + X_OFF);       // aliases x (after xgr/xg2 gemms)
  u16*  encT  = (u16*)(w + ENCT_OFF);
  u16*  wqf   = (u16*)(w + WQF_OFF);
  u16*  wgf   = (u16*)(w + WGF_OFF);
  u16*  wot   = (u16*)(w + WOT_OFF);     // aliases pool (after mega)
  u16*  dech  = (u16*)(w + DECH_OFF);
  float* bas  = (float*)(w + BAS_OFF);
  float* bcr  = (float*)(w + BCR_OFF);
  float* bc2  = (float*)(w + BC2_OFF);
  u16*  wlb   = (u16*)(w + WLB_OFF);
  int*  bar   = (int*)(w + BAR_OFF);
  float* fout = (float*)d_out + (size_t)BT_ * V_;

  hipMemsetAsync(bar, 0, 8192, stream);

  // prologue
  k_gather  <<<BT_, 128, 0, stream>>>(x, embed, target);
  k_biascomb<<<4, 256, 0, stream>>>(bcr, bc2, bas, wlb,
                                    dc_bi, dc_bh, dc_bc, dc_bi2, dc_bh2, dc_bc2,
                                    att_benc, att_bprev, att_wlin);
  k_gemm<<<16 * 8, 256, 0, stream>>>(x, E_, dc_Wi,  H2_, xgr, H_, 0, bcr, 16, 8, E_);
  k_gemm<<<16 * 8, 256, 0, stream>>>(x, E_, dc_Wi2, H_,  xg2, H_, 0, bc2, 16, 8, E_);
  k_gemm<<<16 * 8, 256, 0, stream>>>(enc_h, H2_, att_Wenc, H_, encp, H_, 1, bas, 16, 8, H2_);
  k_transE<<<1024, 256, 0, stream>>>(encT, enc_h);
  k_packq <<<512, 256, 0, stream>>>(wqf, att_Wprev);
  k_packg <<<3072, 256, 0, stream>>>(wgf, dc_Wh, dc_Wc, dc_Wh2, dc_Wc2);

  // the 64-step recurrence: versioned buffers + relaxed leaf-broadcast barriers
  k_mega<<<256, 512, 0, stream>>>(w, dech, fout,
                                  wqf, wgf, encp, encT, xgr, xg2,
                                  prev_s, wlb, bar);

  // vocab projection in two halves (wot aliases dead prologue workspace)
  k_wtrans<<<4000, 256, 0, stream>>>(wot, out_W, 0);
  k_gemm2 <<<2000, 256, 0, stream>>>(dech, wot, (float*)d_out, out_b, 0);
  k_wtrans<<<4000, 256, 0, stream>>>(wot, out_W, 16000);
  k_gemm2 <<<2000, 256, 0, stream>>>(dech, wot, (float*)d_out, out_b, 16000);
}

// Round 8
// 2781.032 us; speedup vs baseline: 1.4767x; 1.1462x over previous
//
#include <hip/hip_runtime.h>

// Sizes
#define B_   32
#define S_   64
#define T_   64
#define H_   1024
#define H2_  2048
#define E_   512
#define V_   32000
#define K3_  3072
#define BT_  2048

typedef unsigned short u16;
typedef __attribute__((ext_vector_type(8))) short short8_t;  // 8 x bf16
typedef __attribute__((ext_vector_type(4))) float f32x4;

__device__ __forceinline__ u16 f2bf(float f) {
  unsigned x = __float_as_uint(f);
  unsigned r = (x + 0x7fffu + ((x >> 16) & 1u)) >> 16;  // RNE
  return (u16)r;
}
__device__ __forceinline__ float bf2f(u16 h) {
  return __uint_as_float(((unsigned)h) << 16);
}
__device__ __forceinline__ float frcp(float x) { return __builtin_amdgcn_rcpf(x); }
__device__ __forceinline__ float ftanh(float x) {
  float e = __expf(2.f * x);
  return 1.f - 2.f * frcp(e + 1.f);
}
__device__ __forceinline__ float fsigm(float x) {
  return frcp(1.f + __expf(-x));
}

#define KEEPV(x) asm volatile("" : "+v"(x))

__device__ __forceinline__ void st_u16(u16* p, u16 v) {
  __hip_atomic_store(p, v, __ATOMIC_RELAXED, __HIP_MEMORY_SCOPE_AGENT);
}
__device__ __forceinline__ void st_f32(float* p, float v) {
  __hip_atomic_store(p, v, __ATOMIC_RELAXED, __HIP_MEMORY_SCOPE_AGENT);
}

// ---------------- workspace layout (bytes) ----------------
#define MB_ (1ull << 20)
#define KB_ (1ull << 10)
#define X_OFF    (0)               // 4MB x (pre-loop) / spp versions (loop) / wot (post)
#define SPP_OFF  (0)               // 64 versions x 64KB
#define XGR_OFF  (4*MB_)           // 8MB (persistent through loop)
#define XG2_OFF  (12*MB_)          // 8MB
#define ENCT_OFF (20*MB_)          // 8MB pre-loop (pinned) — aliased by Xc in loop
#define XCV_OFF  (20*MB_)          // Xc versions t=0..63 x 256KB -> [20,36)
#define ENCP_OFF (28*MB_)          // 4MB pre-loop (pinned) — aliased by Xc[32..47]
#define W2_OFF   (36*MB_)          // 2MB Wprev slices (persistent)
#define WGF_OFF  (38*MB_)          // 24MB pre-loop -> [38,62); aliased by Xs/dech
#define XSV_OFF  (38*MB_)          // Xs versions t=1..64 x 128KB -> [38,46)
#define DECH_OFF (46*MB_)          // 4MB (persistent until gemm2)
#define WOT_OFF  (0)               // 32MB (post-loop only)
#define XS0_OFF  (62*MB_)          // 128KB
#define MB_OFF   (62*MB_ + 128*KB_)  // 128KB mini-bar counters
#define BAR_OFF  (62*MB_ + 256*KB_)  // 8KB
#define WLB_OFF  (62*MB_ + 272*KB_)  // 2KB
#define BCR_OFF  (62*MB_ + 276*KB_)  // 4KB
#define BC2_OFF  (62*MB_ + 280*KB_)  // 4KB

__device__ __forceinline__ u16* xs_hi(char* w, int t) {
  return (u16*)(t == 0 ? (w + XS0_OFF) : (w + XSV_OFF + (size_t)(t - 1) * 131072));
}
__device__ __forceinline__ u16* xc_hi(char* w, int t) {
  return (u16*)(w + XCV_OFF + (size_t)t * 262144);
}
__device__ __forceinline__ float* spp_v(char* w, int t) {
  return (float*)(w + SPP_OFF + (size_t)t * 65536);
}

// ---------------- shared GEMM body (prologue) ----------------
// C[M x N] = A @ B + bias (+bias2); M=mtiles*128, N=ntiles*128
__device__ void gemm_body(char* smemRaw,
                          const float* __restrict__ A, int lda,
                          const float* __restrict__ Bm, int ldb,
                          void* __restrict__ Cv, int ldc, int outBf16,
                          const float* __restrict__ bias, const float* __restrict__ bias2,
                          int mtiles, int ntiles, int K, int bid) {
  u16 (*As)[72] = (u16(*)[72])smemRaw;
  u16 (*Bs)[72] = (u16(*)[72])(smemRaw + 128 * 72 * 2);
  int nwg = mtiles * ntiles;
  int cpx = nwg >> 3;
  int lb = (bid & 7) * cpx + (bid >> 3);
  int ntb = lb / mtiles, mtb = lb - ntb * mtiles;
  size_t m0 = (size_t)mtb * 128, n0 = (size_t)ntb * 128;
  int t = threadIdx.x, lane = t & 63, wid = t >> 6;
  int wr = (wid >> 1) * 64, wc = (wid & 1) * 64;
  f32x4 acc[4][4] = {};
  for (int k0 = 0; k0 < K; k0 += 64) {
    #pragma unroll
    for (int i = 0; i < 8; ++i) {
      int f4 = i * 256 + t;
      int row = f4 >> 4, c4 = (f4 & 15) << 2;
      float4 v = *(const float4*)(A + (m0 + row) * (size_t)lda + k0 + c4);
      ushort4 u; u.x = f2bf(v.x); u.y = f2bf(v.y); u.z = f2bf(v.z); u.w = f2bf(v.w);
      *(ushort4*)&As[row][c4] = u;
    }
    #pragma unroll
    for (int i = 0; i < 8; ++i) {
      int f4 = i * 256 + t;
      int kr = f4 >> 5, c4 = (f4 & 31) << 2;
      float4 v = *(const float4*)(Bm + (size_t)(k0 + kr) * ldb + n0 + c4);
      Bs[c4 + 0][kr] = f2bf(v.x);
      Bs[c4 + 1][kr] = f2bf(v.y);
      Bs[c4 + 2][kr] = f2bf(v.z);
      Bs[c4 + 3][kr] = f2bf(v.w);
    }
    __syncthreads();
    #pragma unroll
    for (int kk = 0; kk < 64; kk += 32) {
      int ko = kk + (lane >> 4) * 8;
      short8_t am[4], bn[4];
      #pragma unroll
      for (int m = 0; m < 4; ++m) am[m] = *(const short8_t*)&As[wr + m * 16 + (lane & 15)][ko];
      #pragma unroll
      for (int n = 0; n < 4; ++n) bn[n] = *(const short8_t*)&Bs[wc + n * 16 + (lane & 15)][ko];
      #pragma unroll
      for (int m = 0; m < 4; ++m)
        #pragma unroll
        for (int n = 0; n < 4; ++n)
          acc[m][n] = __builtin_amdgcn_mfma_f32_16x16x32_bf16(am[m], bn[n], acc[m][n], 0, 0, 0);
    }
    __syncthreads();
  }
  #pragma unroll
  for (int n = 0; n < 4; ++n) {
    int col = wc + n * 16 + (lane & 15);
    float bv = bias ? bias[n0 + col] : 0.f;
    if (bias2) bv += bias2[n0 + col];
    #pragma unroll
    for (int m = 0; m < 4; ++m) {
      size_t row = m0 + wr + m * 16 + ((lane >> 4) << 2);
      #pragma unroll
      for (int r = 0; r < 4; ++r) {
        float val = acc[m][n][r] + bv;
        if (outBf16) ((u16*)Cv)[(row + r) * (size_t)ldc + n0 + col] = f2bf(val);
        else ((float*)Cv)[(row + r) * (size_t)ldc + n0 + col] = val;
      }
    }
  }
}

// ---------------- merged prologue: all independent prep in ONE launch ----------------
// block ranges: [0,1024) gather | [1024,2048) transE | [2048,2560) packq(w2)
//               [2560,5632) packg | [5632,5760) encp gemm | [5760,5764) biases
__global__ __launch_bounds__(256) void k_prep(
    float* __restrict__ x, const float* __restrict__ embed, const int* __restrict__ tgt,
    u16* __restrict__ encT, const float* __restrict__ enc_h,
    u16* __restrict__ w2, const float* __restrict__ Wprev,
    u16* __restrict__ wgf, const float* __restrict__ Wh, const float* __restrict__ Wc,
    const float* __restrict__ Wh2, const float* __restrict__ Wc2,
    u16* __restrict__ encp, const float* __restrict__ Wenc,
    const float* __restrict__ benc, const float* __restrict__ bprev,
    float* __restrict__ bcr, float* __restrict__ bc2o, u16* __restrict__ wlb,
    const float* __restrict__ bi, const float* __restrict__ bh, const float* __restrict__ bc,
    const float* __restrict__ bi2, const float* __restrict__ bh2, const float* __restrict__ bc2i,
    const float* __restrict__ wlin) {
  __shared__ char pbuf[36864];
  const int bid = blockIdx.x, t = threadIdx.x;

  if (bid < 1024) {                       // gather: x[row] = embed[tgt]
    int f4id = bid * 256 + t;
    int row = f4id >> 7, c4 = f4id & 127;
    int tt = row >> 5, bbb = row & 31;
    int trow = tgt[bbb * T_ + tt];
    ((float4*)x)[(size_t)row * 128 + c4] = ((const float4*)embed)[(size_t)trow * 128 + c4];
  } else if (bid < 2048) {                // transE: enc_h -> encT[e][b*64+si]
    u16 (*ld)[68] = (u16(*)[68])pbuf;
    int teb = bid - 1024;
    int b = teb >> 5, et = teb & 31;
    int e0 = et * 64;
    #pragma unroll
    for (int i = 0; i < 4; ++i) {
      int f4 = i * 256 + t;
      int si = f4 >> 4, e4 = (f4 & 15) << 2;
      float4 v = *(const float4*)(enc_h + ((size_t)(b * 64 + si)) * H2_ + e0 + e4);
      ld[si][e4 + 0] = f2bf(v.x); ld[si][e4 + 1] = f2bf(v.y);
      ld[si][e4 + 2] = f2bf(v.z); ld[si][e4 + 3] = f2bf(v.w);
    }
    __syncthreads();
    #pragma unroll
    for (int i = 0; i < 2; ++i) {
      int idx = i * 256 + t;
      int e = idx >> 3, s8 = (idx & 7) << 3;
      short8_t o;
      #pragma unroll
      for (int k = 0; k < 8; ++k) o[k] = (short)ld[s8 + k][e];
      *(short8_t*)(encT + ((size_t)(e0 + e)) * 2048 + b * 64 + s8) = o;
    }
  } else if (bid < 2560) {                // packq: Wprev -> w2[(eg*512+th)*32+i][8]
    float (*ld)[33] = (float(*)[33])pbuf;
    int pb = bid - 2048;
    int kt = pb >> 5, jt = pb & 31;
    int k0 = kt * 64, j0 = jt * 32;
    #pragma unroll
    for (int i = 0; i < 8; ++i) {
      int idx = i * 256 + t; int kr = idx >> 5, jc = idx & 31;
      ld[kr][jc] = Wprev[(size_t)(k0 + kr) * H_ + j0 + jc];
    }
    __syncthreads();
    int jloc = t >> 3, kk8 = t & 7;
    int j = j0 + jloc;
    int eg = j >> 7;
    int th = ((j & 127) << 2) | (kt >> 2);
    int i = ((kt & 3) << 3) | kk8;
    short8_t o;
    #pragma unroll
    for (int e = 0; e < 8; ++e) o[e] = (short)f2bf(ld[kk8 * 8 + e][jloc]);
    *(short8_t*)(w2 + ((size_t)((eg * 512 + th) * 32 + i)) * 8) = o;
  } else if (bid < 5632) {                // packg: gate weights -> wgf frag-major
    float (*ld)[33] = (float(*)[33])pbuf;
    int pgb = bid - 2560;
    int sel = pgb & 1;
    int jt  = (pgb >> 1) & 31;
    int kt  = pgb >> 6;                   // 0..47
    int k0 = kt * 64, j0 = jt * 32;
    const float* srcW = (k0 < H_) ? (sel ? Wh2 : Wh) : (sel ? Wc2 : Wc);
    int ldw = sel ? H_ : H2_;
    int koff = (k0 < H_) ? k0 : (k0 - H_);
    #pragma unroll
    for (int i = 0; i < 8; ++i) {
      int idx = i * 256 + t; int kr = idx >> 5, jc = idx & 31;
      ld[kr][jc] = srcW[(size_t)(koff + kr) * ldw + j0 + jc];
    }
    __syncthreads();
    #pragma unroll
    for (int it = 0; it < 2; ++it) {
      int u = it * 256 + t;
      int m = u & 3, sub = (u >> 2) & 3, kbl = (u >> 4) & 1, islo = (u >> 5) & 1, gg = u >> 6;
      int jjLoc = gg * 4 + m;
      int p = 2 * (j0 + jjLoc) + sel;
      int g = p >> 3, cc = p & 7;
      int c = cc + 8 * islo;
      int KB = kt * 2 + kbl;
      size_t lin = ((size_t)(g * 96 + KB) * 4 + sub) * 16 + c;
      short8_t o;
      #pragma unroll
      for (int j = 0; j < 8; ++j) {
        float v = ld[kbl * 32 + sub * 8 + j][jjLoc];
        u16 h = f2bf(v);
        o[j] = (short)(islo ? f2bf(v - bf2f(h)) : h);
      }
      *(short8_t*)(wgf + lin * 8) = o;
    }
  } else if (bid < 5760) {                // enc_proj gemm (bias = benc + bprev)
    gemm_body(pbuf, enc_h, H2_, Wenc, H_, encp, H_, 1, benc, bprev, 16, 8, H2_, bid - 5632);
  } else {                                // combined biases + wlin bf16
    int j = (bid - 5760) * 256 + t;
    if (j < H_) {
      bcr[j]  = bi[j]  + bh[j]  + bc[j];
      bc2o[j] = bi2[j] + bh2[j] + bc2i[j];
      wlb[j]  = f2bf(wlin[j]);
    }
  }
}

// xgr + xg2 gemms merged: [0,128) xgr, [128,256) xg2
__global__ __launch_bounds__(256) void k_gemm12(
    const float* __restrict__ x,
    const float* __restrict__ Wi, const float* __restrict__ Wi2,
    float* __restrict__ xgr, float* __restrict__ xg2,
    const float* __restrict__ bcr, const float* __restrict__ bc2) {
  __shared__ char pbuf[36864];
  if (blockIdx.x < 128)
    gemm_body(pbuf, x, E_, Wi, H2_, xgr, H_, 0, bcr, nullptr, 16, 8, E_, blockIdx.x);
  else
    gemm_body(pbuf, x, E_, Wi2, H_, xg2, H_, 0, bc2, nullptr, 16, 8, E_, blockIdx.x - 128);
}

// out_W half -> wot bf16 [nLocal 16000][k 1024]
__global__ __launch_bounds__(256) void k_wtrans(u16* __restrict__ wot,
                                                const float* __restrict__ W, int nbase) {
  __shared__ u16 ld[64][68];
  int nt = blockIdx.x % 250, kt = blockIdx.x / 250;
  int n0 = nbase + nt * 64, k0 = kt * 64;
  int t = threadIdx.x;
  #pragma unroll
  for (int i = 0; i < 4; ++i) {
    int f4 = i * 256 + t;
    int kr = f4 >> 4, n4 = (f4 & 15) << 2;
    float4 v = *(const float4*)(W + (size_t)(k0 + kr) * V_ + n0 + n4);
    ld[kr][n4 + 0] = f2bf(v.x); ld[kr][n4 + 1] = f2bf(v.y);
    ld[kr][n4 + 2] = f2bf(v.z); ld[kr][n4 + 3] = f2bf(v.w);
  }
  __syncthreads();
  #pragma unroll
  for (int i = 0; i < 2; ++i) {
    int idx = i * 256 + t;
    int n = idx >> 3, k8 = (idx & 7) << 3;
    short8_t o;
    #pragma unroll
    for (int k = 0; k < 8; ++k) o[k] = (short)ld[k8 + k][n];
    *(short8_t*)(wot + ((size_t)(nt * 64 + n)) * H_ + k0 + k8) = o;
  }
}

// final GEMM: dech bf16 [2048][1024] @ wot^T -> C fp32 (per 16000-col half)
__global__ __launch_bounds__(256) void k_gemm2(
    const u16* __restrict__ A, const u16* __restrict__ Bt,
    float* __restrict__ C, const float* __restrict__ bias, int n0g) {
  __shared__ u16 As[128][72];
  __shared__ u16 Bs[128][72];
  int bid = blockIdx.x;
  int lb = (bid & 7) * 250 + (bid >> 3);
  int mtb = lb & 15, ntb = lb >> 4;
  size_t m0 = (size_t)mtb * 128;
  size_t nl0 = (size_t)ntb * 128;
  int t = threadIdx.x, lane = t & 63, wid = t >> 6;
  int wr = (wid >> 1) * 64, wc = (wid & 1) * 64;
  f32x4 acc[4][4] = {};
  for (int k0 = 0; k0 < H_; k0 += 64) {
    #pragma unroll
    for (int i = 0; i < 4; ++i) {
      int idx = i * 256 + t;
      int row = idx >> 3, c8 = (idx & 7) << 3;
      *(short8_t*)&As[row][c8] = *(const short8_t*)(A + (m0 + row) * H_ + k0 + c8);
      *(short8_t*)&Bs[row][c8] = *(const short8_t*)(Bt + (nl0 + row) * H_ + k0 + c8);
    }
    __syncthreads();
    #pragma unroll
    for (int kk = 0; kk < 64; kk += 32) {
      int ko = kk + (lane >> 4) * 8;
      short8_t am[4], bn[4];
      #pragma unroll
      for (int m = 0; m < 4; ++m) am[m] = *(const short8_t*)&As[wr + m * 16 + (lane & 15)][ko];
      #pragma unroll
      for (int n = 0; n < 4; ++n) bn[n] = *(const short8_t*)&Bs[wc + n * 16 + (lane & 15)][ko];
      #pragma unroll
      for (int m = 0; m < 4; ++m)
        #pragma unroll
        for (int n = 0; n < 4; ++n)
          acc[m][n] = __builtin_amdgcn_mfma_f32_16x16x32_bf16(am[m], bn[n], acc[m][n], 0, 0, 0);
    }
    __syncthreads();
  }
  #pragma unroll
  for (int n = 0; n < 4; ++n) {
    int col = n0g + (int)nl0 + wc + n * 16 + (lane & 15);
    float bv = bias[col];
    #pragma unroll
    for (int m = 0; m < 4; ++m) {
      size_t row = m0 + wr + m * 16 + ((lane >> 4) << 2);
      #pragma unroll
      for (int r = 0; r < 4; ++r)
        C[(row + r) * (size_t)V_ + col] = acc[m][n][r] + bv;
    }
  }
}

// ---------------- persistent decoder kernel ----------------

// relaxed leaf-broadcast barrier (versioned buffers give freshness)
__device__ __forceinline__ void gridbar(int* bar, int target) {
  asm volatile("s_waitcnt vmcnt(0)" ::: "memory");
  __syncthreads();
  if (threadIdx.x == 0) {
    int* leafcnt = bar;
    int* root    = bar + 512;
    int* leafep  = bar + 768;
    int li = blockIdx.x >> 3;
    if (__hip_atomic_fetch_add(&leafcnt[li * 16], 1, __ATOMIC_RELAXED, __HIP_MEMORY_SCOPE_AGENT) == 7) {
      __hip_atomic_store(&leafcnt[li * 16], 0, __ATOMIC_RELAXED, __HIP_MEMORY_SCOPE_AGENT);
      if (__hip_atomic_fetch_add(root, 1, __ATOMIC_RELAXED, __HIP_MEMORY_SCOPE_AGENT) == 31) {
        __hip_atomic_store(root, 0, __ATOMIC_RELAXED, __HIP_MEMORY_SCOPE_AGENT);
        #pragma unroll
        for (int i = 0; i < 32; ++i)
          __hip_atomic_store(&leafep[i * 16], target, __ATOMIC_RELAXED, __HIP_MEMORY_SCOPE_AGENT);
      }
    }
    while (__hip_atomic_load(&leafep[li * 16], __ATOMIC_RELAXED, __HIP_MEMORY_SCOPE_AGENT) != target)
      __builtin_amdgcn_s_sleep(2);
  }
  __syncthreads();
}

#define MFMA16(a, b, c) __builtin_amdgcn_mfma_f32_16x16x32_bf16((a), (b), (c), 0, 0, 0)

__global__ __launch_bounds__(512, 1) void k_mega(
    char* w, u16* __restrict__ dech, float* __restrict__ fout,
    const u16* __restrict__ w2, const u16* __restrict__ wgf,
    const u16* __restrict__ encp, const u16* __restrict__ encT,
    const float* __restrict__ xgr, const float* __restrict__ xg2,
    const float* __restrict__ prev_s, const u16* __restrict__ wlb,
    int* bar, int* mb) {
  const int t = threadIdx.x, blk = blockIdx.x;
  const int lane = t & 63, wid = t >> 6;
  const int l15 = lane & 15, l4 = lane >> 4;
  const int klo = l4 * 8;
  __shared__ short8_t wg_lds[6144];   // 96KB gate weights
  __shared__ f32x4 scr[1024];         // 16KB reduce scratch
  __shared__ float sc[64];
  __shared__ u16 sL[1024];            // s[bb] staging (bf16 hi)
  __shared__ float qL[128];           // q j-slice
  int ep = 0;

  for (int i = t; i < 6144; i += 512)
    wg_lds[i] = *(const short8_t*)(wgf + ((size_t)blk * 6144 + i) * 8);

  const int bb = blk >> 3, eg = blk & 7;

  // ---- pinned register operands ----
  // phase A scores: thread = (si_a = t>>3, jg = t&7), j = eg*128 + jg*16 + jj
  const int si_a = t >> 3, jg = t & 7;
  short8_t epv2[2], wlv2[2];
  {
    const u16* p = encp + ((size_t)(bb * 64 + si_a)) * H_ + eg * 128 + jg * 16;
    epv2[0] = *(const short8_t*)(p);     KEEPV(epv2[0]);
    epv2[1] = *(const short8_t*)(p + 8); KEEPV(epv2[1]);
    const u16* q = wlb + eg * 128 + jg * 16;
    wlv2[0] = *(const short8_t*)(q);     KEEPV(wlv2[0]);
    wlv2[1] = *(const short8_t*)(q + 8); KEEPV(wlv2[1]);
  }
  // ctx: thread = (eloc = t>>1, half = t&1)
  const int eloc = t >> 1, half = t & 1;
  const int ecol = eg * 256 + eloc;
  short8_t et[4];
  #pragma unroll
  for (int i = 0; i < 4; ++i) {
    et[i] = *(const short8_t*)(encT + (size_t)ecol * 2048 + bb * 64 + half * 32 + i * 8);
    KEEPV(et[i]);
  }

  // finalizer constants + fp32 state in registers
  const int pc4 = blk * 8 + l15, jcol = pc4 >> 1, isc = pc4 & 1;
  const int rb = wid * 16 + l4 * 4;
  const bool fin = (wid < 2) && (l15 < 8);
  float sreg[4] = {0.f, 0.f, 0.f, 0.f};

  // P0: init Xs[0] + register state
  {
    int idx = blk * 512 + t;
    u16* xs0h = xs_hi(w, 0);
    u16* xs0l = xs0h + B_ * H_;
    if (idx < B_ * H_) {
      float v = prev_s[idx];
      u16 h = f2bf(v);
      st_u16(&xs0h[idx], h);
      st_u16(&xs0l[idx], f2bf(v - bf2f(h)));
    }
    if (fin) {
      #pragma unroll
      for (int r = 0; r < 4; ++r) sreg[r] = prev_s[(rb + r) * H_ + jcol];
    }
  }
  gridbar(bar, ++ep);

  for (int ts = 0; ts < T_; ++ts) {
    const u16* xsh = xs_hi(w, ts);
    const u16* xsl = xsh + B_ * H_;
    u16* xch = xc_hi(w, ts);
    u16* xcl = xch + B_ * H2_;
    float* spp = spp_v(w, ts);
    int* mbp = mb + (ts * 32 + bb) * 16;

    // step-top prefetches (overlap phase A)
    float xv[4] = {0.f, 0.f, 0.f, 0.f};
    if (fin) {
      const float* xg = isc ? xg2 : xgr;
      #pragma unroll
      for (int r = 0; r < 4; ++r)
        xv[r] = xg[((size_t)ts * B_ + rb + r) * H_ + jcol];
    }
    short8_t pA[4], pB[4];
    #pragma unroll
    for (int i = 0; i < 4; ++i) {
      int k = (wid + 8 * i) * 32 + klo;
      pA[i] = *(const short8_t*)(xsh + l15 * H_ + k);        KEEPV(pA[i]);
      pB[i] = *(const short8_t*)(xsh + (l15 + 16) * H_ + k); KEEPV(pB[i]);
    }

    // ---- Phase A: q j-slice (w2 from L2) + partial scores ----
    if (t < 128)
      *(short8_t*)&sL[t * 8] = *(const short8_t*)(xsh + bb * H_ + t * 8);
    __syncthreads();
    {
      // thread: j = eg*128 + (t>>2), kq = t&3 (256-k chunk)
      float qa = 0.f;
      const u16* wp = w2 + ((size_t)(eg * 512 + t)) * 256;
      const u16* sp = sL + (t & 3) * 256;
      #pragma unroll
      for (int i = 0; i < 32; ++i) {
        short8_t wv = *(const short8_t*)(wp + i * 8);
        short8_t sv = *(const short8_t*)(sp + i * 8);
        #pragma unroll
        for (int e = 0; e < 8; ++e)
          qa += bf2f((u16)wv[e]) * bf2f((u16)sv[e]);
      }
      qa += __shfl_xor(qa, 1, 64);
      qa += __shfl_xor(qa, 2, 64);
      if ((t & 3) == 0) qL[t >> 2] = qa;
    }
    __syncthreads();
    {
      float p = 0.f;
      #pragma unroll
      for (int jj = 0; jj < 16; ++jj) {
        float qv = qL[jg * 16 + jj];
        p += ftanh(bf2f((u16)epv2[jj >> 3][jj & 7]) + qv) * bf2f((u16)wlv2[jj >> 3][jj & 7]);
      }
      p += __shfl_xor(p, 1, 64);
      p += __shfl_xor(p, 2, 64);
      p += __shfl_xor(p, 4, 64);
      if (jg == 0) st_f32(&spp[(bb * 64 + si_a) * 8 + eg], p);
    }
    // ---- mini-barrier: 8 blocks of this batch item ----
    asm volatile("s_waitcnt vmcnt(0)" ::: "memory");
    __syncthreads();
    if (t == 0) {
      __hip_atomic_fetch_add(mbp, 1, __ATOMIC_RELAXED, __HIP_MEMORY_SCOPE_AGENT);
      while (__hip_atomic_load(mbp, __ATOMIC_RELAXED, __HIP_MEMORY_SCOPE_AGENT) != 8)
        __builtin_amdgcn_s_sleep(1);
    }
    __syncthreads();

    // ---- Phase B: sum partials + softmax + ctx ----
    if (wid == 0) {
      const float* pp = spp + ((size_t)(bb * 64 + lane)) * 8;
      float4 a0 = *(const float4*)(pp);
      float4 a1 = *(const float4*)(pp + 4);
      float v = (a0.x + a0.y + a0.z + a0.w) + (a1.x + a1.y + a1.z + a1.w);
      float m = v;
      #pragma unroll
      for (int off = 32; off; off >>= 1) m = fmaxf(m, __shfl_xor(m, off, 64));
      float e = __expf(v - m);
      float s = e;
      #pragma unroll
      for (int off = 32; off; off >>= 1) s += __shfl_xor(s, off, 64);
      sc[lane] = e * frcp(s);
    }
    __syncthreads();
    {
      float a = 0.f;
      #pragma unroll
      for (int i = 0; i < 4; ++i)
        #pragma unroll
        for (int j = 0; j < 8; ++j)
          a += sc[half * 32 + i * 8 + j] * bf2f((u16)et[i][j]);
      a += __shfl_xor(a, 1, 64);
      if (half == 0) {
        u16 hh = f2bf(a);
        st_u16(&xch[bb * H2_ + ecol], hh);
        st_u16(&xcl[bb * H2_ + ecol], f2bf(a - bf2f(hh)));
      }
    }
    gridbar(bar, ++ep);

    // ---- P3: gates ([s|ctx] @ Wcat split-bf16, B from LDS) + state update ----
    {
      f32x4 aA = {}, aB = {};
      short8_t loA[4], loB[4];
      #pragma unroll
      for (int i = 0; i < 4; ++i) {
        int k = (wid + 8 * i) * 32 + klo;
        loA[i] = *(const short8_t*)(xsl + l15 * H_ + k);
        loB[i] = *(const short8_t*)(xsl + (l15 + 16) * H_ + k);
      }
      #pragma unroll
      for (int i = 0; i < 4; ++i) {
        short8_t bv = wg_lds[(wid + 8 * i) * 64 + lane];
        aA = MFMA16(pA[i], bv, aA);
        aB = MFMA16(pB[i], bv, aB);
      }
      #pragma unroll
      for (int i = 0; i < 4; ++i) {
        short8_t bv = wg_lds[(wid + 8 * i) * 64 + lane];
        aA = MFMA16(loA[i], bv, aA);
        aB = MFMA16(loB[i], bv, aB);
      }
      #pragma unroll
      for (int i = 4; i < 12; ++i) {
        int kb = wid + 8 * i;
        int k = kb * 32 + klo - H_;
        short8_t hA = *(const short8_t*)(xch + l15 * H2_ + k);
        short8_t lA = *(const short8_t*)(xcl + l15 * H2_ + k);
        short8_t hB = *(const short8_t*)(xch + (l15 + 16) * H2_ + k);
        short8_t lB = *(const short8_t*)(xcl + (l15 + 16) * H2_ + k);
        short8_t bv = wg_lds[kb * 64 + lane];
        aA = MFMA16(hA, bv, aA);
        aA = MFMA16(lA, bv, aA);
        aB = MFMA16(hB, bv, aB);
        aB = MFMA16(lB, bv, aB);
      }
      scr[(wid * 2 + 0) * 64 + lane] = aA;
      scr[(wid * 2 + 1) * 64 + lane] = aB;
      __syncthreads();
      if (wid < 2) {
        f32x4 s = scr[wid * 64 + lane];
        #pragma unroll
        for (int i = 1; i < 8; ++i) s += scr[(i * 2 + wid) * 64 + lane];
        float tot[4];
        #pragma unroll
        for (int r = 0; r < 4; ++r) tot[r] = s[r] + __shfl_xor(s[r], 8, 64);
        if (l15 < 8) {
          u16* nsh = xs_hi(w, ts + 1);
          u16* nsl = nsh + B_ * H_;
          #pragma unroll
          for (int r = 0; r < 4; ++r) {
            int brow = rb + r;
            float pre = tot[r] + xv[r];
            float mate = __shfl_xor(pre, 1, 64);
            float rpre = isc ? mate : pre;
            float cpre = isc ? pre : mate;
            float rg = fsigm(rpre);
            float cg = ftanh(cpre);
            float sp = sreg[r];
            float sn = sp + rg * (cg - sp);
            sreg[r] = sn;
            if (!isc) {
              u16 hh = f2bf(sn);
              st_u16(&nsh[brow * H_ + jcol], hh);
              st_u16(&nsl[brow * H_ + jcol], f2bf(sn - bf2f(hh)));
              dech[((size_t)brow * T_ + ts) * H_ + jcol] = hh;
              if (ts == T_ - 1) fout[brow * H_ + jcol] = sn;
            }
          }
        }
      }
    }
    gridbar(bar, ++ep);
  }
}

// ---------------- host ----------------

extern "C" void kernel_launch(void* const* d_in, const int* in_sizes, int n_in,
                              void* d_out, int out_size, void* d_ws, size_t ws_size,
                              hipStream_t stream) {
  const float* enc_h    = (const float*)d_in[0];
  const float* prev_s   = (const float*)d_in[1];
  const int*   target   = (const int*)d_in[2];
  const float* embed    = (const float*)d_in[3];
  const float* att_Wenc = (const float*)d_in[4];
  const float* att_benc = (const float*)d_in[5];
  const float* att_Wprev= (const float*)d_in[6];
  const float* att_bprev= (const float*)d_in[7];
  const float* att_wlin = (const float*)d_in[8];
  const float* dc_Wi    = (const float*)d_in[10];
  const float* dc_bi    = (const float*)d_in[11];
  const float* dc_Wh    = (const float*)d_in[12];
  const float* dc_bh    = (const float*)d_in[13];
  const float* dc_Wc    = (const float*)d_in[14];
  const float* dc_bc    = (const float*)d_in[15];
  const float* dc_Wi2   = (const float*)d_in[16];
  const float* dc_bi2   = (const float*)d_in[17];
  const float* dc_Wh2   = (const float*)d_in[18];
  const float* dc_bh2   = (const float*)d_in[19];
  const float* dc_Wc2   = (const float*)d_in[20];
  const float* dc_bc2   = (const float*)d_in[21];
  const float* out_W    = (const float*)d_in[22];
  const float* out_b    = (const float*)d_in[23];

  char* w = (char*)d_ws;
  float* x    = (float*)(w + X_OFF);
  float* xgr  = (float*)(w + XGR_OFF);
  float* xg2  = (float*)(w + XG2_OFF);
  u16*  encT  = (u16*)(w + ENCT_OFF);
  u16*  encp  = (u16*)(w + ENCP_OFF);
  u16*  w2    = (u16*)(w + W2_OFF);
  u16*  wgf   = (u16*)(w + WGF_OFF);
  u16*  wot   = (u16*)(w + WOT_OFF);
  u16*  dech  = (u16*)(w + DECH_OFF);
  u16*  wlb   = (u16*)(w + WLB_OFF);
  float* bcr  = (float*)(w + BCR_OFF);
  float* bc2  = (float*)(w + BC2_OFF);
  int*  bar   = (int*)(w + BAR_OFF);
  int*  mb    = (int*)(w + MB_OFF);
  float* fout = (float*)d_out + (size_t)BT_ * V_;

  hipMemsetAsync(w + MB_OFF, 0, 136 * KB_, stream);   // mb + bar

  // prologue: 2 launches
  k_prep<<<5764, 256, 0, stream>>>(x, embed, target, encT, enc_h,
                                   w2, att_Wprev, wgf, dc_Wh, dc_Wc, dc_Wh2, dc_Wc2,
                                   encp, att_Wenc, att_benc, att_bprev,
                                   bcr, bc2, wlb,
                                   dc_bi, dc_bh, dc_bc, dc_bi2, dc_bh2, dc_bc2, att_wlin);
  k_gemm12<<<256, 256, 0, stream>>>(x, dc_Wi, dc_Wi2, xgr, xg2, bcr, bc2);

  // 64-step recurrence: 2 full barriers + 1 per-b mini-barrier per step
  k_mega<<<256, 512, 0, stream>>>(w, dech, fout,
                                  w2, wgf, encp, encT, xgr, xg2,
                                  prev_s, wlb, bar, mb);

  // vocab projection in two halves (wot aliases dead loop workspace)
  k_wtrans<<<4000, 256, 0, stream>>>(wot, out_W, 0);
  k_gemm2 <<<2000, 256, 0, stream>>>(dech, wot, (float*)d_out, out_b, 0);
  k_wtrans<<<4000, 256, 0, stream>>>(wot, out_W, 16000);
  k_gemm2 <<<2000, 256, 0, stream>>>(dech, wot, (float*)d_out, out_b, 16000);
}